// Round 1
// 583.677 us; speedup vs baseline: 1.0071x; 1.0071x over previous
//
#include <hip/hip_runtime.h>

// LinearTransformerBlock on MI355X — R6.
// R5 post-mortem: gemm_qkv = 295 µs (50% of total) at MfmaUtil 31%, HBM 12%,
// 2.5e7 bank conflicts — classic m97 2-barrier-structure ceiling (~700 TF).
// R6: port gemm_qkv + gemm_out to the 256x256 8-phase template (T3+T4 counted
// vmcnt, T2 XOR-swizzle via pre-swizzled global source, T5 setprio, T1 XCD
// swizzle). 512 thr / 8 waves / 128 KiB LDS dbuf / BK=64. Raw s_barrier +
// asm waitcnt (no __syncthreads vmcnt(0) drain). Hazard-audited schedule:
// all ds_reads of a buffer complete in P1-P2; restages of that buffer land in
// P2-P4 (>=1 barrier after last read). Ledger: prologue 14 gll16/wave ->
// vmcnt(6); steady boundary vmcnt(6); t=30 drains vmcnt(0).

typedef unsigned short u16;
typedef __attribute__((ext_vector_type(8))) short bf16x8;
typedef __attribute__((ext_vector_type(4))) float f32x4;

__device__ __forceinline__ float bf2f(u16 u) {
    union { unsigned int i; float f; } x; x.i = ((unsigned int)u) << 16; return x.f;
}
__device__ __forceinline__ u16 f2bf(float f) {
    union { unsigned int i; float f; } x; x.f = f;
    unsigned int i = x.i;
    return (u16)((i + 0x7fffu + ((i >> 16) & 1u)) >> 16);   // RNE
}
__device__ __forceinline__ uint4 pack8(const float* __restrict__ src) {
    float4 f0 = *(const float4*)(src);
    float4 f1 = *(const float4*)(src + 4);
    union { u16 u[8]; uint4 v; } P;
    P.u[0] = f2bf(f0.x); P.u[1] = f2bf(f0.y); P.u[2] = f2bf(f0.z); P.u[3] = f2bf(f0.w);
    P.u[4] = f2bf(f1.x); P.u[5] = f2bf(f1.y); P.u[6] = f2bf(f1.z); P.u[7] = f2bf(f1.w);
    return P.v;
}
__device__ __forceinline__ void gll16(void* lds, const void* g) {
    __builtin_amdgcn_global_load_lds(
        (const __attribute__((address_space(1))) unsigned int*)g,
        (__attribute__((address_space(3))) unsigned int*)lds, 16, 0, 0);
}

// ---------------------------------------------------------------------------
// Kernel 0: one-launch fp32 -> bf16 cast of X, Wq, Wk, Wv, Wo.
// ---------------------------------------------------------------------------
__global__ __launch_bounds__(256) void cast_all(
    const float* __restrict__ x,  const float* __restrict__ Wq,
    const float* __restrict__ Wk, const float* __restrict__ Wv,
    const float* __restrict__ Wo,
    u16* __restrict__ Xb, u16* __restrict__ Wqkvb, u16* __restrict__ Wob)
{
    int bid = blockIdx.x, t = threadIdx.x;
    const float* s; u16* d; size_t i;
    if (bid < 8192)       { s = x;  d = Xb;              i = (size_t)bid * 256 + t; }
    else if (bid < 10240) { s = Wq; d = Wqkvb;           i = (size_t)(bid - 8192)  * 256 + t; }
    else if (bid < 12288) { s = Wk; d = Wqkvb + 4194304; i = (size_t)(bid - 10240) * 256 + t; }
    else if (bid < 14336) { s = Wv; d = Wqkvb + 8388608; i = (size_t)(bid - 12288) * 256 + t; }
    else                  { s = Wo; d = Wob;             i = (size_t)(bid - 14336) * 256 + t; }
    *(uint4*)(d + i * 8) = pack8(s + i * 8);
}

// ---------------------------------------------------------------------------
// 256x256 bf16 MFMA main loop over K=2048 (32 K-tiles of BK=64).
// 8 waves (2M x 4N), per-wave 128x64 output = acc[8][4].
// LDS: A,B each [2 buf][256 rows][64 cols] bf16, rows = 128 B.
// Swizzle: LDS row r, 16B-granule slot g holds global granule g ^ (r&7).
//   - staging: gll16 dest linear; per-lane source granule = (l&7)^(l>>3)
//     (rows advance every 8 lanes, so (l>>3) == row&7 for that lane's row).
//   - ds_read: granule = nominal ^ (row&7).
// Phase schedule per K-tile t (buf = t&1):
//   P1: ds_read B n0-3 kk0-1 + A m0-1 (12); stage (t+1) B-h1 -> nbuf;
//       BAR; lgkm0; prio1; 16 MFMA m0-1; prio0; BAR
//   P2: ds_read A m2-7 (12); stage (t+2) B-h0 -> buf; BAR; lgkm0; MFMA m2-3; BAR
//   P3: stage (t+2) A-h0 -> buf; BAR; MFMA m4-5; BAR
//   P4: stage (t+2) A-h1 -> buf; BAR; MFMA m6-7; vmcnt(6); BAR
// ---------------------------------------------------------------------------
__device__ __forceinline__ void mm256_loop(
    const u16* __restrict__ gA, const u16* __restrict__ gB,
    int w, int wm, int wn, int quad, int l16,
    f32x4 (&acc)[8][4])
{
    __shared__ __align__(16) u16 As[2 * 16384];
    __shared__ __align__(16) u16 Bs[2 * 16384];

    const size_t CH = 64 * 2048;     // 64-row chunk advance in A/B elements

#define SGA(buf, c, koff) gll16(As + (buf) * 16384 + (c) * 4096 + w * 512, \
                                gA + (size_t)(c) * CH + (koff))
#define SGB(buf, c, koff) gll16(Bs + (buf) * 16384 + (c) * 4096 + w * 512, \
                                gB + (size_t)(c) * CH + (koff))

    // Prologue: tile0 {A-h0,A-h1,B-h0,B-h1}; tile1 {B-h0, A-h0, A-h1}.
    SGA(0, 0, 0); SGA(0, 1, 0); SGA(0, 2, 0); SGA(0, 3, 0);
    SGB(0, 0, 0); SGB(0, 1, 0); SGB(0, 2, 0); SGB(0, 3, 0);
    SGB(1, 0, 64); SGB(1, 1, 64);
    SGA(1, 0, 64); SGA(1, 1, 64); SGA(1, 2, 64); SGA(1, 3, 64);
    asm volatile("s_waitcnt vmcnt(6)" ::: "memory");   // tile0 landed; 6 in flight
    __builtin_amdgcn_s_barrier();

    const u16* A0 = As + wm * 8192;   // wave's 128-row A half
    const u16* B0 = Bs + wn * 4096;   // wave's 64-row B slice

#pragma unroll 2
    for (int t = 0; t < 32; ++t) {
        const int buf = t & 1, nbuf = buf ^ 1;
        const u16* Ab = A0 + buf * 16384;
        const u16* Bb = B0 + buf * 16384;
        const int k1 = (t + 1) * 64, k2 = (t + 2) * 64;

        // ---------------- Phase 1 ----------------
        bf16x8 bF[4][2], aT[2][2];
#pragma unroll
        for (int n = 0; n < 4; n++)
#pragma unroll
            for (int kk = 0; kk < 2; kk++) {
                int row = n * 16 + l16;
                bF[n][kk] = *(const bf16x8*)(Bb + row * 64 + ((((kk << 2) + quad) ^ (row & 7)) << 3));
            }
#pragma unroll
        for (int m = 0; m < 2; m++)
#pragma unroll
            for (int kk = 0; kk < 2; kk++) {
                int row = m * 16 + l16;
                aT[m][kk] = *(const bf16x8*)(Ab + row * 64 + ((((kk << 2) + quad) ^ (row & 7)) << 3));
            }
        if (t < 31) { SGB(nbuf, 2, k1); SGB(nbuf, 3, k1); }
        __builtin_amdgcn_s_barrier();
        asm volatile("s_waitcnt lgkmcnt(0)" ::: "memory");
        __builtin_amdgcn_s_setprio(1);
#pragma unroll
        for (int m = 0; m < 2; m++)
#pragma unroll
            for (int n = 0; n < 4; n++)
#pragma unroll
                for (int kk = 0; kk < 2; kk++)
                    acc[m][n] = __builtin_amdgcn_mfma_f32_16x16x32_bf16(aT[m][kk], bF[n][kk], acc[m][n], 0, 0, 0);
        __builtin_amdgcn_s_setprio(0);
        __builtin_amdgcn_s_barrier();

        // ---------------- Phase 2 ----------------
        bf16x8 aR[6][2];
#pragma unroll
        for (int m = 0; m < 6; m++)
#pragma unroll
            for (int kk = 0; kk < 2; kk++) {
                int row = (m + 2) * 16 + l16;
                aR[m][kk] = *(const bf16x8*)(Ab + row * 64 + ((((kk << 2) + quad) ^ (row & 7)) << 3));
            }
        if (t < 30) { SGB(buf, 0, k2); SGB(buf, 1, k2); }
        __builtin_amdgcn_s_barrier();
        asm volatile("s_waitcnt lgkmcnt(0)" ::: "memory");
        __builtin_amdgcn_s_setprio(1);
#pragma unroll
        for (int m = 0; m < 2; m++)
#pragma unroll
            for (int n = 0; n < 4; n++)
#pragma unroll
                for (int kk = 0; kk < 2; kk++)
                    acc[2 + m][n] = __builtin_amdgcn_mfma_f32_16x16x32_bf16(aR[m][kk], bF[n][kk], acc[2 + m][n], 0, 0, 0);
        __builtin_amdgcn_s_setprio(0);
        __builtin_amdgcn_s_barrier();

        // ---------------- Phase 3 ----------------
        if (t < 30) { SGA(buf, 0, k2); SGA(buf, 1, k2); }
        __builtin_amdgcn_s_barrier();
        __builtin_amdgcn_s_setprio(1);
#pragma unroll
        for (int m = 0; m < 2; m++)
#pragma unroll
            for (int n = 0; n < 4; n++)
#pragma unroll
                for (int kk = 0; kk < 2; kk++)
                    acc[4 + m][n] = __builtin_amdgcn_mfma_f32_16x16x32_bf16(aR[2 + m][kk], bF[n][kk], acc[4 + m][n], 0, 0, 0);
        __builtin_amdgcn_s_setprio(0);
        __builtin_amdgcn_s_barrier();

        // ---------------- Phase 4 ----------------
        if (t < 30) { SGA(buf, 2, k2); SGA(buf, 3, k2); }
        __builtin_amdgcn_s_barrier();
        __builtin_amdgcn_s_setprio(1);
#pragma unroll
        for (int m = 0; m < 2; m++)
#pragma unroll
            for (int n = 0; n < 4; n++)
#pragma unroll
                for (int kk = 0; kk < 2; kk++)
                    acc[6 + m][n] = __builtin_amdgcn_mfma_f32_16x16x32_bf16(aR[4 + m][kk], bF[n][kk], acc[6 + m][n], 0, 0, 0);
        __builtin_amdgcn_s_setprio(0);
        if (t < 30)       asm volatile("s_waitcnt vmcnt(6)" ::: "memory");
        else if (t == 30) asm volatile("s_waitcnt vmcnt(0)" ::: "memory");
        __builtin_amdgcn_s_barrier();
    }
#undef SGA
#undef SGB
}

// ---------------------------------------------------------------------------
// Kernel 1: QKV projection + bias + RoPE + ReLU. 256^2 8-phase template.
// Grid: 768 WGs (32 m-tiles x 3 regions x 8 n-tiles), XCD-swizzled.
// ---------------------------------------------------------------------------
__global__ __launch_bounds__(512, 1) void gemm_qkv(
    const u16* __restrict__ Xb, const u16* __restrict__ Wqkvb,
    const float* __restrict__ bq, const float* __restrict__ bk, const float* __restrict__ bv,
    const float* __restrict__ cosT, const float* __restrict__ sinT,
    u16* __restrict__ Q, u16* __restrict__ K, u16* __restrict__ V)
{
    int t = threadIdx.x, w = t >> 6, lane = t & 63, quad = lane >> 4, l16 = lane & 15;
    int wm = w >> 2, wn = w & 3;

    int wg = (blockIdx.x & 7) * 96 + (blockIdx.x >> 3);   // 768 % 8 == 0: bijective
    int bm = wg & 31, bn = wg >> 5;                        // consecutive wg share B panel
    int region = bn >> 3;
    const u16*   W    = Wqkvb + (size_t)region * 4194304;
    const float* bias = (region == 0) ? bq : (region == 1 ? bk : bv);
    u16* OUT          = (region == 0) ? Q  : (region == 1 ? K  : V);
    int m0 = bm << 8, n0 = (bn & 7) << 8;

    int lr8 = lane >> 3, lg = (lane & 7) ^ lr8;           // pre-swizzled source granule
    const u16* gA = Xb + (size_t)(m0 + w * 8 + lr8) * 2048 + lg * 8;
    const u16* gB = W  + (size_t)(n0 + w * 8 + lr8) * 2048 + lg * 8;

    f32x4 acc[8][4] = {};
    mm256_loop(gA, gB, w, wm, wn, quad, l16, acc);

#pragma unroll
    for (int i = 0; i < 8; i++) {
#pragma unroll
        for (int j = 0; j < 4; j++) {
            int nc   = n0 + wn * 64 + j * 16 + l16;
            int h    = nc >> 7, dpos = nc & 127;
            float bia = bias[nc];
#pragma unroll
            for (int r = 0; r < 4; r++) {
                int mr = m0 + wm * 128 + i * 16 + quad * 4 + r;   // C/D: row = quad*4+reg
                int b  = mr >> 12, s = mr & 4095;
                float val = acc[i][j][r] + bia;
                if (region < 2) {
                    float pair = __shfl_xor(val, 1, 64);
                    float c  = cosT[s * 128 + dpos];
                    float sn = sinT[s * 128 + dpos];
                    val = fmaxf(val * c + ((dpos & 1) ? pair : -pair) * sn, 0.f);
                }
                OUT[((size_t)(b * 16 + h) * 4096 + s) * 128 + dpos] = f2bf(val);
            }
        }
    }
}

// ---------------------------------------------------------------------------
// Kernel 2: ksum[bh][d] = sum_s K[bh][s][d]  (atomic partial per 512-s block).
// ---------------------------------------------------------------------------
__global__ __launch_bounds__(256) void ksum_kernel(
    const u16* __restrict__ Kb, float* __restrict__ ksumbuf)
{
    int bh = blockIdx.x, sc8 = blockIdx.y, t = threadIdx.x;
    int dpair = (t & 63) * 2, sq = t >> 6;
    const u16* base = Kb + (size_t)bh * 524288 + (size_t)(sc8 * 512 + sq * 128) * 128 + dpair;
    float s0 = 0.f, s1 = 0.f;
#pragma unroll 8
    for (int r = 0; r < 128; r++) {
        unsigned int wv = *(const unsigned int*)(base + (size_t)r * 128);
        s0 += bf2f((u16)(wv & 0xffff));
        s1 += bf2f((u16)(wv >> 16));
    }
    __shared__ float red[4][128];
    red[sq][dpair]     = s0;
    red[sq][dpair + 1] = s1;
    __syncthreads();
    if (t < 128) {
        float tot = red[0][t] + red[1][t] + red[2][t] + red[3][t];
        atomicAdd(&ksumbuf[bh * 128 + t], tot);
    }
}

// ---------------------------------------------------------------------------
// Kernel 3: vk partials via MFMA. Per (bh, sk): C[128n][128d] = sum_s V[s,n]K[s,d]
// over 512 s. Operands staged transposed into LDS (swizzled).
// ---------------------------------------------------------------------------
__global__ __launch_bounds__(256) void vk_mfma(
    const u16* __restrict__ Kb, const u16* __restrict__ Vb, float* __restrict__ part)
{
    int bh = blockIdx.x;          // 0..31
    int sk = blockIdx.y;          // 0..7
    int t  = threadIdx.x;
    int s0 = sk * 512;

    __shared__ __align__(16) u16 Kt[128 * 32];
    __shared__ __align__(16) u16 Vt[128 * 32];

    const u16* Kp = Kb + (size_t)bh * 524288;
    const u16* Vp = Vb + (size_t)bh * 524288;

    int dgrp  = t & 15;
    int d0    = dgrp * 8;
    int spair = (t >> 4) * 2;
    int sg    = spair >> 3;

    int w = t >> 6, lane = t & 63, quad = lane >> 4, l16 = lane & 15;
    int nbase = (w >> 1) * 64, dbase = (w & 1) * 64;

    f32x4 acc[4][4] = {};

    for (int tile = 0; tile < 16; tile++) {
        int st = s0 + tile * 32;
        __syncthreads();
        {
            const u16* kg = Kp + (size_t)(st + spair) * 128 + d0;
            const u16* vg = Vp + (size_t)(st + spair) * 128 + d0;
            union { uint4 v; u16 u[8]; } ka, kb, va, vb;
            ka.v = *(const uint4*)kg;  kb.v = *(const uint4*)(kg + 128);
            va.v = *(const uint4*)vg;  vb.v = *(const uint4*)(vg + 128);
            int swz = (((sg + dgrp) & 3) << 3) + (spair & 7);
#pragma unroll
            for (int i = 0; i < 8; i++) {
                int e = (d0 + i) * 32 + swz;
                *(unsigned int*)(Kt + e) = (unsigned int)ka.u[i] | ((unsigned int)kb.u[i] << 16);
                *(unsigned int*)(Vt + e) = (unsigned int)va.u[i] | ((unsigned int)vb.u[i] << 16);
            }
        }
        __syncthreads();

        bf16x8 af[4], bfr[4];
#pragma unroll
        for (int i = 0; i < 4; i++) {
            int r = nbase + i * 16 + l16;
            af[i] = *(const bf16x8*)(Vt + r * 32 + (((quad + (r >> 3)) & 3) << 3));
        }
#pragma unroll
        for (int j = 0; j < 4; j++) {
            int r = dbase + j * 16 + l16;
            bfr[j] = *(const bf16x8*)(Kt + r * 32 + (((quad + (r >> 3)) & 3) << 3));
        }
#pragma unroll
        for (int i = 0; i < 4; i++)
#pragma unroll
            for (int j = 0; j < 4; j++)
                acc[i][j] = __builtin_amdgcn_mfma_f32_16x16x32_bf16(af[i], bfr[j], acc[i][j], 0, 0, 0);
    }

    float* dst = part + (size_t)(bh * 8 + sk) * 16384;
#pragma unroll
    for (int i = 0; i < 4; i++) {
#pragma unroll
        for (int j = 0; j < 4; j++) {
#pragma unroll
            for (int r = 0; r < 4; r++) {
                int n = nbase + i * 16 + quad * 4 + r;
                int d = dbase + j * 16 + l16;
                dst[n * 128 + d] = acc[i][j][r];
            }
        }
    }
}

// ---------------------------------------------------------------------------
// Kernel 4: reduce 8 partials -> vkb[32][128*128] bf16 (hs consumes bf16).
// ---------------------------------------------------------------------------
__global__ __launch_bounds__(256) void vk_reduce(const float* __restrict__ part,
                                                 u16* __restrict__ vkb)
{
    int bh = blockIdx.x, by = blockIdx.y, t = threadIdx.x;
    int end = (by + 1) * 2048;
    for (int idx = by * 2048 + t; idx < end; idx += 256) {
        float s = 0.f;
#pragma unroll
        for (int p = 0; p < 8; p++) s += part[(size_t)(bh * 8 + p) * 16384 + idx];
        vkb[(size_t)bh * 16384 + idx] = f2bf(s);
    }
}

// ---------------------------------------------------------------------------
// Kernel 5: hs via MFMA, denominator fused. Per (bh, sc):
// hs[128s,128n] = (q @ vk^T) * rden, rden = 1/(q . ksum + eps). vk is bf16.
// ---------------------------------------------------------------------------
__global__ __launch_bounds__(256) void hs_mfma(
    const u16* __restrict__ Qb, const u16* __restrict__ vkb,
    const float* __restrict__ ksumbuf, u16* __restrict__ HS)
{
    int bh = blockIdx.x, sc = blockIdx.y;
    __shared__ __align__(16) u16 qL[128 * 136];
    __shared__ __align__(16) u16 vkL[128 * 136];
    __shared__ float rdL[128];
    __shared__ float ksumL[128];
    int t = threadIdx.x;

    const u16* Qp   = Qb  + ((size_t)bh * 4096 + sc * 128) * 128;
    const u16* vsrc = vkb + (size_t)bh * 16384;
    int row = t >> 4, colc = (t & 15) * 8;
#pragma unroll
    for (int r8 = 0; r8 < 8; r8++) {
        int rr = row + r8 * 16;
        *(uint4*)(qL  + rr * 136 + colc) = *(const uint4*)(Qp   + (size_t)rr * 128 + colc);
        *(uint4*)(vkL + rr * 136 + colc) = *(const uint4*)(vsrc + (size_t)rr * 128 + colc);
    }
    if (t < 128) ksumL[t] = ksumbuf[bh * 128 + t];
    __syncthreads();

    // Fused denominator: thread pair (srow, half).
    {
        int srow = t >> 1, half = t & 1;
        const u16*   q  = qL + srow * 136 + half * 64;
        const float* kp = ksumL + half * 64;
        float p = 0.f;
#pragma unroll 8
        for (int d = 0; d < 64; d += 4) {
            ushort4 qv = *(const ushort4*)(q + d);
            p += bf2f(qv.x) * kp[d] + bf2f(qv.y) * kp[d + 1]
               + bf2f(qv.z) * kp[d + 2] + bf2f(qv.w) * kp[d + 3];
        }
        p += __shfl_xor(p, 1, 64);
        if (half == 0) rdL[srow] = 1.0f / (p + 1e-15f);
    }

    int w = t >> 6, lane = t & 63, quad = lane >> 4, l16 = lane & 15;
    int wm0 = (w >> 1) * 64, wn0 = (w & 1) * 64;
    f32x4 acc[4][4] = {};
#pragma unroll
    for (int ks = 0; ks < 4; ks++) {
        bf16x8 af[4], bfr[4];
#pragma unroll
        for (int i = 0; i < 4; i++) af[i]  = *(const bf16x8*)(qL  + (wm0 + i * 16 + l16) * 136 + ks * 32 + quad * 8);
#pragma unroll
        for (int j = 0; j < 4; j++) bfr[j] = *(const bf16x8*)(vkL + (wn0 + j * 16 + l16) * 136 + ks * 32 + quad * 8);
#pragma unroll
        for (int i = 0; i < 4; i++)
#pragma unroll
            for (int j = 0; j < 4; j++)
                acc[i][j] = __builtin_amdgcn_mfma_f32_16x16x32_bf16(af[i], bfr[j], acc[i][j], 0, 0, 0);
    }
    __syncthreads();   // rdL ready

    int b = bh >> 4, h = bh & 15;
#pragma unroll
    for (int i = 0; i < 4; i++) {
#pragma unroll
        for (int j = 0; j < 4; j++) {
#pragma unroll
            for (int r = 0; r < 4; r++) {
                int sl = wm0 + i * 16 + quad * 4 + r;
                int n  = wn0 + j * 16 + l16;
                size_t srow = (size_t)b * 4096 + sc * 128 + sl;
                HS[srow * 2048 + h * 128 + n] = f2bf(acc[i][j][r] * rdL[sl]);
            }
        }
    }
}

// ---------------------------------------------------------------------------
// Kernel 6: out = HS @ Wo^T + bo, 256^2 8-phase template, fp32 out.
// Grid: 256 WGs (32 m-tiles x 8 n-tiles), XCD-swizzled, exactly 1/CU.
// ---------------------------------------------------------------------------
__global__ __launch_bounds__(512, 1) void gemm_out(
    const u16* __restrict__ HSm, const u16* __restrict__ Wob,
    const float* __restrict__ bo, float* __restrict__ OUT)
{
    int t = threadIdx.x, w = t >> 6, lane = t & 63, quad = lane >> 4, l16 = lane & 15;
    int wm = w >> 2, wn = w & 3;

    int wg = (blockIdx.x & 7) * 32 + (blockIdx.x >> 3);   // 256 % 8 == 0: bijective
    int bm = wg & 31, bn = wg >> 5;
    int m0 = bm << 8, n0 = bn << 8;

    int lr8 = lane >> 3, lg = (lane & 7) ^ lr8;
    const u16* gA = HSm + (size_t)(m0 + w * 8 + lr8) * 2048 + lg * 8;
    const u16* gB = Wob + (size_t)(n0 + w * 8 + lr8) * 2048 + lg * 8;

    f32x4 acc[8][4] = {};
    mm256_loop(gA, gB, w, wm, wn, quad, l16, acc);

#pragma unroll
    for (int i = 0; i < 8; i++) {
#pragma unroll
        for (int j = 0; j < 4; j++) {
            int nc = n0 + wn * 64 + j * 16 + l16;
            float bia = bo[nc];
#pragma unroll
            for (int r = 0; r < 4; r++) {
                int mr = m0 + wm * 128 + i * 16 + quad * 4 + r;
                OUT[(size_t)mr * 2048 + nc] = acc[i][j][r] + bia;
            }
        }
    }
}

// ---------------------------------------------------------------------------
extern "C" void kernel_launch(void* const* d_in, const int* in_sizes, int n_in,
                              void* d_out, int out_size, void* d_ws, size_t ws_size,
                              hipStream_t stream) {
    const float* x    = (const float*)d_in[0];
    const float* cosT = (const float*)d_in[1];
    const float* sinT = (const float*)d_in[2];
    const float* Wq   = (const float*)d_in[3];
    const float* bq   = (const float*)d_in[4];
    const float* Wk   = (const float*)d_in[5];
    const float* bk   = (const float*)d_in[6];
    const float* Wv   = (const float*)d_in[7];
    const float* bv   = (const float*)d_in[8];
    const float* Wo   = (const float*)d_in[9];
    const float* bo   = (const float*)d_in[10];

    char* ws = (char*)d_ws;
    u16*   Wqkvb   = (u16*)(ws);                 // 25,165,824 B
    u16*   Wob     = (u16*)(ws + 25165824);      //  8,388,608 B
    u16*   Xb      = (u16*)(ws + 33554432);      // 33,554,432 B (dead after gemm_qkv)
    float* part    = (float*)(ws + 33554432);    // alias Xb: 16,777,216 B
    u16*   V       = (u16*)(ws + 67108864);      // 33,554,432 B
    u16*   HS      = V;                          // V dead after vk_mfma
    u16*   vkb     = (u16*)(ws + 100663296);     //  1,048,576 B (bf16)
    float* ksumbuf = (float*)(ws + 101711872);   //     16,384 B -> ~101.7 MB total

    // Q, K scratch in d_out (exactly 67,108,864 B); dead before gemm_out writes.
    u16* Q  = (u16*)d_out;
    u16* Kb = (u16*)d_out + 16777216;

    hipMemsetAsync(ksumbuf, 0, 32 * 128 * sizeof(float), stream);
    cast_all<<<16384, 256, 0, stream>>>(x, Wq, Wk, Wv, Wo, Xb, Wqkvb, Wob);
    gemm_qkv<<<768, 512, 0, stream>>>(Xb, Wqkvb, bq, bk, bv, cosT, sinT, Q, Kb, V);
    ksum_kernel<<<dim3(32, 8), 256, 0, stream>>>(Kb, ksumbuf);
    vk_mfma<<<dim3(32, 8), 256, 0, stream>>>(Kb, V, part);
    vk_reduce<<<dim3(32, 8), 256, 0, stream>>>(part, vkb);
    hs_mfma<<<dim3(32, 32), 256, 0, stream>>>(Q, vkb, ksumbuf, HS);
    gemm_out<<<256, 512, 0, stream>>>(HS, Wob, bo, (float*)d_out);
}

// Round 2
// 545.528 us; speedup vs baseline: 1.0775x; 1.0699x over previous
//
#include <hip/hip_runtime.h>

// LinearTransformerBlock on MI355X — R7.
// R6 post-mortem: 256^2 8-phase landed at 313 µs, MfmaUtil 28.5, conflicts 0,
// but FETCH_SIZE exploded 184->438 MB (unique inputs = 56 MB): the XCD swizzle
// made every XCD stream all of X (32 MB) from L3/HBM each round (768 MB
// cross-XCD demand, 57% HBM-miss), and with 1 WG/CU every miss lands on the
// P4 vmcnt(6) stall -> 7800 cyc/tile vs ~1024 floor.
// R7: grid remap only (schedule untouched). XCD x owns A-panels bm ≡ x (mod 8):
// per XCD per round = 4 A-panels (4 MB, 8 concurrent readers, K-lockstep ->
// L2-resident) x 8 B-panels (24 MB unique weights via L3). A-panels identical
// across rounds -> unique A/XCD = 4 MB per dispatch. Round r == region r.
// Same remap for gemm_out. Both bijective (verified).

typedef unsigned short u16;
typedef __attribute__((ext_vector_type(8))) short bf16x8;
typedef __attribute__((ext_vector_type(4))) float f32x4;

__device__ __forceinline__ float bf2f(u16 u) {
    union { unsigned int i; float f; } x; x.i = ((unsigned int)u) << 16; return x.f;
}
__device__ __forceinline__ u16 f2bf(float f) {
    union { unsigned int i; float f; } x; x.f = f;
    unsigned int i = x.i;
    return (u16)((i + 0x7fffu + ((i >> 16) & 1u)) >> 16);   // RNE
}
__device__ __forceinline__ uint4 pack8(const float* __restrict__ src) {
    float4 f0 = *(const float4*)(src);
    float4 f1 = *(const float4*)(src + 4);
    union { u16 u[8]; uint4 v; } P;
    P.u[0] = f2bf(f0.x); P.u[1] = f2bf(f0.y); P.u[2] = f2bf(f0.z); P.u[3] = f2bf(f0.w);
    P.u[4] = f2bf(f1.x); P.u[5] = f2bf(f1.y); P.u[6] = f2bf(f1.z); P.u[7] = f2bf(f1.w);
    return P.v;
}
__device__ __forceinline__ void gll16(void* lds, const void* g) {
    __builtin_amdgcn_global_load_lds(
        (const __attribute__((address_space(1))) unsigned int*)g,
        (__attribute__((address_space(3))) unsigned int*)lds, 16, 0, 0);
}

// ---------------------------------------------------------------------------
// Kernel 0: one-launch fp32 -> bf16 cast of X, Wq, Wk, Wv, Wo.
// ---------------------------------------------------------------------------
__global__ __launch_bounds__(256) void cast_all(
    const float* __restrict__ x,  const float* __restrict__ Wq,
    const float* __restrict__ Wk, const float* __restrict__ Wv,
    const float* __restrict__ Wo,
    u16* __restrict__ Xb, u16* __restrict__ Wqkvb, u16* __restrict__ Wob)
{
    int bid = blockIdx.x, t = threadIdx.x;
    const float* s; u16* d; size_t i;
    if (bid < 8192)       { s = x;  d = Xb;              i = (size_t)bid * 256 + t; }
    else if (bid < 10240) { s = Wq; d = Wqkvb;           i = (size_t)(bid - 8192)  * 256 + t; }
    else if (bid < 12288) { s = Wk; d = Wqkvb + 4194304; i = (size_t)(bid - 10240) * 256 + t; }
    else if (bid < 14336) { s = Wv; d = Wqkvb + 8388608; i = (size_t)(bid - 12288) * 256 + t; }
    else                  { s = Wo; d = Wob;             i = (size_t)(bid - 14336) * 256 + t; }
    *(uint4*)(d + i * 8) = pack8(s + i * 8);
}

// ---------------------------------------------------------------------------
// 256x256 bf16 MFMA main loop over K=2048 (32 K-tiles of BK=64).
// 8 waves (2M x 4N), per-wave 128x64 output = acc[8][4].
// LDS: A,B each [2 buf][256 rows][64 cols] bf16, rows = 128 B.
// Swizzle: LDS row r, 16B-granule slot g holds global granule g ^ (r&7).
//   - staging: gll16 dest linear; per-lane source granule = (l&7)^(l>>3).
//   - ds_read: granule = nominal ^ (row&7).
// Phase schedule per K-tile t (buf = t&1):
//   P1: ds_read B n0-3 kk0-1 + A m0-1 (12); stage (t+1) B-h1 -> nbuf;
//       BAR; lgkm0; prio1; 16 MFMA m0-1; prio0; BAR
//   P2: ds_read A m2-7 (12); stage (t+2) B-h0 -> buf; BAR; lgkm0; MFMA m2-3; BAR
//   P3: stage (t+2) A-h0 -> buf; BAR; MFMA m4-5; BAR
//   P4: stage (t+2) A-h1 -> buf; BAR; MFMA m6-7; vmcnt(6); BAR
// Hazard audit: all ds_reads of a buffer complete in P1-P2 (lgkm0 before each
// wave's MFMA, before the P2-exit barrier); restages of that buffer issue in
// P2-P4, after that barrier. vmcnt(6) at P4 drains through P1's stage.
// ---------------------------------------------------------------------------
__device__ __forceinline__ void mm256_loop(
    const u16* __restrict__ gA, const u16* __restrict__ gB,
    int w, int wm, int wn, int quad, int l16,
    f32x4 (&acc)[8][4])
{
    __shared__ __align__(16) u16 As[2 * 16384];
    __shared__ __align__(16) u16 Bs[2 * 16384];

    const size_t CH = 64 * 2048;     // 64-row chunk advance in A/B elements

#define SGA(buf, c, koff) gll16(As + (buf) * 16384 + (c) * 4096 + w * 512, \
                                gA + (size_t)(c) * CH + (koff))
#define SGB(buf, c, koff) gll16(Bs + (buf) * 16384 + (c) * 4096 + w * 512, \
                                gB + (size_t)(c) * CH + (koff))

    // Prologue: tile0 {A-h0,A-h1,B-h0,B-h1}; tile1 {B-h0, A-h0, A-h1}.
    SGA(0, 0, 0); SGA(0, 1, 0); SGA(0, 2, 0); SGA(0, 3, 0);
    SGB(0, 0, 0); SGB(0, 1, 0); SGB(0, 2, 0); SGB(0, 3, 0);
    SGB(1, 0, 64); SGB(1, 1, 64);
    SGA(1, 0, 64); SGA(1, 1, 64); SGA(1, 2, 64); SGA(1, 3, 64);
    asm volatile("s_waitcnt vmcnt(6)" ::: "memory");   // tile0 landed; 6 in flight
    __builtin_amdgcn_s_barrier();

    const u16* A0 = As + wm * 8192;   // wave's 128-row A half
    const u16* B0 = Bs + wn * 4096;   // wave's 64-row B slice

#pragma unroll 2
    for (int t = 0; t < 32; ++t) {
        const int buf = t & 1, nbuf = buf ^ 1;
        const u16* Ab = A0 + buf * 16384;
        const u16* Bb = B0 + buf * 16384;
        const int k1 = (t + 1) * 64, k2 = (t + 2) * 64;

        // ---------------- Phase 1 ----------------
        bf16x8 bF[4][2], aT[2][2];
#pragma unroll
        for (int n = 0; n < 4; n++)
#pragma unroll
            for (int kk = 0; kk < 2; kk++) {
                int row = n * 16 + l16;
                bF[n][kk] = *(const bf16x8*)(Bb + row * 64 + ((((kk << 2) + quad) ^ (row & 7)) << 3));
            }
#pragma unroll
        for (int m = 0; m < 2; m++)
#pragma unroll
            for (int kk = 0; kk < 2; kk++) {
                int row = m * 16 + l16;
                aT[m][kk] = *(const bf16x8*)(Ab + row * 64 + ((((kk << 2) + quad) ^ (row & 7)) << 3));
            }
        if (t < 31) { SGB(nbuf, 2, k1); SGB(nbuf, 3, k1); }
        __builtin_amdgcn_s_barrier();
        asm volatile("s_waitcnt lgkmcnt(0)" ::: "memory");
        __builtin_amdgcn_s_setprio(1);
#pragma unroll
        for (int m = 0; m < 2; m++)
#pragma unroll
            for (int n = 0; n < 4; n++)
#pragma unroll
                for (int kk = 0; kk < 2; kk++)
                    acc[m][n] = __builtin_amdgcn_mfma_f32_16x16x32_bf16(aT[m][kk], bF[n][kk], acc[m][n], 0, 0, 0);
        __builtin_amdgcn_s_setprio(0);
        __builtin_amdgcn_s_barrier();

        // ---------------- Phase 2 ----------------
        bf16x8 aR[6][2];
#pragma unroll
        for (int m = 0; m < 6; m++)
#pragma unroll
            for (int kk = 0; kk < 2; kk++) {
                int row = (m + 2) * 16 + l16;
                aR[m][kk] = *(const bf16x8*)(Ab + row * 64 + ((((kk << 2) + quad) ^ (row & 7)) << 3));
            }
        if (t < 30) { SGB(buf, 0, k2); SGB(buf, 1, k2); }
        __builtin_amdgcn_s_barrier();
        asm volatile("s_waitcnt lgkmcnt(0)" ::: "memory");
        __builtin_amdgcn_s_setprio(1);
#pragma unroll
        for (int m = 0; m < 2; m++)
#pragma unroll
            for (int n = 0; n < 4; n++)
#pragma unroll
                for (int kk = 0; kk < 2; kk++)
                    acc[2 + m][n] = __builtin_amdgcn_mfma_f32_16x16x32_bf16(aR[m][kk], bF[n][kk], acc[2 + m][n], 0, 0, 0);
        __builtin_amdgcn_s_setprio(0);
        __builtin_amdgcn_s_barrier();

        // ---------------- Phase 3 ----------------
        if (t < 30) { SGA(buf, 0, k2); SGA(buf, 1, k2); }
        __builtin_amdgcn_s_barrier();
        __builtin_amdgcn_s_setprio(1);
#pragma unroll
        for (int m = 0; m < 2; m++)
#pragma unroll
            for (int n = 0; n < 4; n++)
#pragma unroll
                for (int kk = 0; kk < 2; kk++)
                    acc[4 + m][n] = __builtin_amdgcn_mfma_f32_16x16x32_bf16(aR[2 + m][kk], bF[n][kk], acc[4 + m][n], 0, 0, 0);
        __builtin_amdgcn_s_setprio(0);
        __builtin_amdgcn_s_barrier();

        // ---------------- Phase 4 ----------------
        if (t < 30) { SGA(buf, 2, k2); SGA(buf, 3, k2); }
        __builtin_amdgcn_s_barrier();
        __builtin_amdgcn_s_setprio(1);
#pragma unroll
        for (int m = 0; m < 2; m++)
#pragma unroll
            for (int n = 0; n < 4; n++)
#pragma unroll
                for (int kk = 0; kk < 2; kk++)
                    acc[6 + m][n] = __builtin_amdgcn_mfma_f32_16x16x32_bf16(aR[4 + m][kk], bF[n][kk], acc[6 + m][n], 0, 0, 0);
        __builtin_amdgcn_s_setprio(0);
        if (t < 30)       asm volatile("s_waitcnt vmcnt(6)" ::: "memory");
        else if (t == 30) asm volatile("s_waitcnt vmcnt(0)" ::: "memory");
        __builtin_amdgcn_s_barrier();
    }
#undef SGA
#undef SGB
}

// ---------------------------------------------------------------------------
// Kernel 1: QKV projection + bias + RoPE + ReLU. 256^2 8-phase template.
// Grid remap (R7): bid -> r=bid>>8 (round == region), x=bid&7 (XCD),
// k=(bid&255)>>3; bm = x + 8*(k&3) (XCD-private A panels), bn = 8r + (k>>2).
// Per XCD per round: 4 A-panels (L2-resident, 8 concurrent readers each)
// x 8 B-panels (L3). Bijective: k = ((bn&7)<<2)|(bm>>3), x = bm&7, r = bn>>3.
// ---------------------------------------------------------------------------
__global__ __launch_bounds__(512, 1) void gemm_qkv(
    const u16* __restrict__ Xb, const u16* __restrict__ Wqkvb,
    const float* __restrict__ bq, const float* __restrict__ bk, const float* __restrict__ bv,
    const float* __restrict__ cosT, const float* __restrict__ sinT,
    u16* __restrict__ Q, u16* __restrict__ K, u16* __restrict__ V)
{
    int t = threadIdx.x, w = t >> 6, lane = t & 63, quad = lane >> 4, l16 = lane & 15;
    int wm = w >> 2, wn = w & 3;

    int bid = blockIdx.x;
    int r = bid >> 8, i = bid & 255, x = i & 7, k = i >> 3;
    int bm = x + ((k & 3) << 3);          // XCD x owns bm ≡ x (mod 8)
    int bn = (r << 3) + (k >> 2);         // round r covers bn ∈ [8r, 8r+8)
    int region = r;                        // == bn >> 3
    const u16*   W    = Wqkvb + (size_t)region * 4194304;
    const float* bias = (region == 0) ? bq : (region == 1 ? bk : bv);
    u16* OUT          = (region == 0) ? Q  : (region == 1 ? K  : V);
    int m0 = bm << 8, n0 = (bn & 7) << 8;

    int lr8 = lane >> 3, lg = (lane & 7) ^ lr8;           // pre-swizzled source granule
    const u16* gA = Xb + (size_t)(m0 + w * 8 + lr8) * 2048 + lg * 8;
    const u16* gB = W  + (size_t)(n0 + w * 8 + lr8) * 2048 + lg * 8;

    f32x4 acc[8][4] = {};
    mm256_loop(gA, gB, w, wm, wn, quad, l16, acc);

#pragma unroll
    for (int i2 = 0; i2 < 8; i2++) {
#pragma unroll
        for (int j = 0; j < 4; j++) {
            int nc   = n0 + wn * 64 + j * 16 + l16;
            int h    = nc >> 7, dpos = nc & 127;
            float bia = bias[nc];
#pragma unroll
            for (int rr = 0; rr < 4; rr++) {
                int mr = m0 + wm * 128 + i2 * 16 + quad * 4 + rr;   // C/D: row = quad*4+reg
                int b  = mr >> 12, s = mr & 4095;
                float val = acc[i2][j][rr] + bia;
                if (region < 2) {
                    float pair = __shfl_xor(val, 1, 64);
                    float c  = cosT[s * 128 + dpos];
                    float sn = sinT[s * 128 + dpos];
                    val = fmaxf(val * c + ((dpos & 1) ? pair : -pair) * sn, 0.f);
                }
                OUT[((size_t)(b * 16 + h) * 4096 + s) * 128 + dpos] = f2bf(val);
            }
        }
    }
}

// ---------------------------------------------------------------------------
// Kernel 2: ksum[bh][d] = sum_s K[bh][s][d]  (atomic partial per 512-s block).
// ---------------------------------------------------------------------------
__global__ __launch_bounds__(256) void ksum_kernel(
    const u16* __restrict__ Kb, float* __restrict__ ksumbuf)
{
    int bh = blockIdx.x, sc8 = blockIdx.y, t = threadIdx.x;
    int dpair = (t & 63) * 2, sq = t >> 6;
    const u16* base = Kb + (size_t)bh * 524288 + (size_t)(sc8 * 512 + sq * 128) * 128 + dpair;
    float s0 = 0.f, s1 = 0.f;
#pragma unroll 8
    for (int r = 0; r < 128; r++) {
        unsigned int wv = *(const unsigned int*)(base + (size_t)r * 128);
        s0 += bf2f((u16)(wv & 0xffff));
        s1 += bf2f((u16)(wv >> 16));
    }
    __shared__ float red[4][128];
    red[sq][dpair]     = s0;
    red[sq][dpair + 1] = s1;
    __syncthreads();
    if (t < 128) {
        float tot = red[0][t] + red[1][t] + red[2][t] + red[3][t];
        atomicAdd(&ksumbuf[bh * 128 + t], tot);
    }
}

// ---------------------------------------------------------------------------
// Kernel 3: vk partials via MFMA. Per (bh, sk): C[128n][128d] = sum_s V[s,n]K[s,d]
// over 512 s. Operands staged transposed into LDS (swizzled).
// ---------------------------------------------------------------------------
__global__ __launch_bounds__(256) void vk_mfma(
    const u16* __restrict__ Kb, const u16* __restrict__ Vb, float* __restrict__ part)
{
    int bh = blockIdx.x;          // 0..31
    int sk = blockIdx.y;          // 0..7
    int t  = threadIdx.x;
    int s0 = sk * 512;

    __shared__ __align__(16) u16 Kt[128 * 32];
    __shared__ __align__(16) u16 Vt[128 * 32];

    const u16* Kp = Kb + (size_t)bh * 524288;
    const u16* Vp = Vb + (size_t)bh * 524288;

    int dgrp  = t & 15;
    int d0    = dgrp * 8;
    int spair = (t >> 4) * 2;
    int sg    = spair >> 3;

    int w = t >> 6, lane = t & 63, quad = lane >> 4, l16 = lane & 15;
    int nbase = (w >> 1) * 64, dbase = (w & 1) * 64;

    f32x4 acc[4][4] = {};

    for (int tile = 0; tile < 16; tile++) {
        int st = s0 + tile * 32;
        __syncthreads();
        {
            const u16* kg = Kp + (size_t)(st + spair) * 128 + d0;
            const u16* vg = Vp + (size_t)(st + spair) * 128 + d0;
            union { uint4 v; u16 u[8]; } ka, kb, va, vb;
            ka.v = *(const uint4*)kg;  kb.v = *(const uint4*)(kg + 128);
            va.v = *(const uint4*)vg;  vb.v = *(const uint4*)(vg + 128);
            int swz = (((sg + dgrp) & 3) << 3) + (spair & 7);
#pragma unroll
            for (int i = 0; i < 8; i++) {
                int e = (d0 + i) * 32 + swz;
                *(unsigned int*)(Kt + e) = (unsigned int)ka.u[i] | ((unsigned int)kb.u[i] << 16);
                *(unsigned int*)(Vt + e) = (unsigned int)va.u[i] | ((unsigned int)vb.u[i] << 16);
            }
        }
        __syncthreads();

        bf16x8 af[4], bfr[4];
#pragma unroll
        for (int i = 0; i < 4; i++) {
            int r = nbase + i * 16 + l16;
            af[i] = *(const bf16x8*)(Vt + r * 32 + (((quad + (r >> 3)) & 3) << 3));
        }
#pragma unroll
        for (int j = 0; j < 4; j++) {
            int r = dbase + j * 16 + l16;
            bfr[j] = *(const bf16x8*)(Kt + r * 32 + (((quad + (r >> 3)) & 3) << 3));
        }
#pragma unroll
        for (int i = 0; i < 4; i++)
#pragma unroll
            for (int j = 0; j < 4; j++)
                acc[i][j] = __builtin_amdgcn_mfma_f32_16x16x32_bf16(af[i], bfr[j], acc[i][j], 0, 0, 0);
    }

    float* dst = part + (size_t)(bh * 8 + sk) * 16384;
#pragma unroll
    for (int i = 0; i < 4; i++) {
#pragma unroll
        for (int j = 0; j < 4; j++) {
#pragma unroll
            for (int r = 0; r < 4; r++) {
                int n = nbase + i * 16 + quad * 4 + r;
                int d = dbase + j * 16 + l16;
                dst[n * 128 + d] = acc[i][j][r];
            }
        }
    }
}

// ---------------------------------------------------------------------------
// Kernel 4: reduce 8 partials -> vkb[32][128*128] bf16 (hs consumes bf16).
// ---------------------------------------------------------------------------
__global__ __launch_bounds__(256) void vk_reduce(const float* __restrict__ part,
                                                 u16* __restrict__ vkb)
{
    int bh = blockIdx.x, by = blockIdx.y, t = threadIdx.x;
    int end = (by + 1) * 2048;
    for (int idx = by * 2048 + t; idx < end; idx += 256) {
        float s = 0.f;
#pragma unroll
        for (int p = 0; p < 8; p++) s += part[(size_t)(bh * 8 + p) * 16384 + idx];
        vkb[(size_t)bh * 16384 + idx] = f2bf(s);
    }
}

// ---------------------------------------------------------------------------
// Kernel 5: hs via MFMA, denominator fused. Per (bh, sc):
// hs[128s,128n] = (q @ vk^T) * rden, rden = 1/(q . ksum + eps). vk is bf16.
// ---------------------------------------------------------------------------
__global__ __launch_bounds__(256) void hs_mfma(
    const u16* __restrict__ Qb, const u16* __restrict__ vkb,
    const float* __restrict__ ksumbuf, u16* __restrict__ HS)
{
    int bh = blockIdx.x, sc = blockIdx.y;
    __shared__ __align__(16) u16 qL[128 * 136];
    __shared__ __align__(16) u16 vkL[128 * 136];
    __shared__ float rdL[128];
    __shared__ float ksumL[128];
    int t = threadIdx.x;

    const u16* Qp   = Qb  + ((size_t)bh * 4096 + sc * 128) * 128;
    const u16* vsrc = vkb + (size_t)bh * 16384;
    int row = t >> 4, colc = (t & 15) * 8;
#pragma unroll
    for (int r8 = 0; r8 < 8; r8++) {
        int rr = row + r8 * 16;
        *(uint4*)(qL  + rr * 136 + colc) = *(const uint4*)(Qp   + (size_t)rr * 128 + colc);
        *(uint4*)(vkL + rr * 136 + colc) = *(const uint4*)(vsrc + (size_t)rr * 128 + colc);
    }
    if (t < 128) ksumL[t] = ksumbuf[bh * 128 + t];
    __syncthreads();

    // Fused denominator: thread pair (srow, half).
    {
        int srow = t >> 1, half = t & 1;
        const u16*   q  = qL + srow * 136 + half * 64;
        const float* kp = ksumL + half * 64;
        float p = 0.f;
#pragma unroll 8
        for (int d = 0; d < 64; d += 4) {
            ushort4 qv = *(const ushort4*)(q + d);
            p += bf2f(qv.x) * kp[d] + bf2f(qv.y) * kp[d + 1]
               + bf2f(qv.z) * kp[d + 2] + bf2f(qv.w) * kp[d + 3];
        }
        p += __shfl_xor(p, 1, 64);
        if (half == 0) rdL[srow] = 1.0f / (p + 1e-15f);
    }

    int w = t >> 6, lane = t & 63, quad = lane >> 4, l16 = lane & 15;
    int wm0 = (w >> 1) * 64, wn0 = (w & 1) * 64;
    f32x4 acc[4][4] = {};
#pragma unroll
    for (int ks = 0; ks < 4; ks++) {
        bf16x8 af[4], bfr[4];
#pragma unroll
        for (int i = 0; i < 4; i++) af[i]  = *(const bf16x8*)(qL  + (wm0 + i * 16 + l16) * 136 + ks * 32 + quad * 8);
#pragma unroll
        for (int j = 0; j < 4; j++) bfr[j] = *(const bf16x8*)(vkL + (wn0 + j * 16 + l16) * 136 + ks * 32 + quad * 8);
#pragma unroll
        for (int i = 0; i < 4; i++)
#pragma unroll
            for (int j = 0; j < 4; j++)
                acc[i][j] = __builtin_amdgcn_mfma_f32_16x16x32_bf16(af[i], bfr[j], acc[i][j], 0, 0, 0);
    }
    __syncthreads();   // rdL ready

    int b = bh >> 4, h = bh & 15;
#pragma unroll
    for (int i = 0; i < 4; i++) {
#pragma unroll
        for (int j = 0; j < 4; j++) {
#pragma unroll
            for (int r = 0; r < 4; r++) {
                int sl = wm0 + i * 16 + quad * 4 + r;
                int n  = wn0 + j * 16 + l16;
                size_t srow = (size_t)b * 4096 + sc * 128 + sl;
                HS[srow * 2048 + h * 128 + n] = f2bf(acc[i][j][r] * rdL[sl]);
            }
        }
    }
}

// ---------------------------------------------------------------------------
// Kernel 6: out = HS @ Wo^T + bo, 256^2 8-phase template, fp32 out.
// Grid remap (R7): XCD x owns bm ≡ x (mod 8); bn = k>>2. Bijective.
// ---------------------------------------------------------------------------
__global__ __launch_bounds__(512, 1) void gemm_out(
    const u16* __restrict__ HSm, const u16* __restrict__ Wob,
    const float* __restrict__ bo, float* __restrict__ OUT)
{
    int t = threadIdx.x, w = t >> 6, lane = t & 63, quad = lane >> 4, l16 = lane & 15;
    int wm = w >> 2, wn = w & 3;

    int x = blockIdx.x & 7, k = blockIdx.x >> 3;
    int bm = x + ((k & 3) << 3);          // XCD x owns bm ≡ x (mod 8)
    int bn = k >> 2;
    int m0 = bm << 8, n0 = bn << 8;

    int lr8 = lane >> 3, lg = (lane & 7) ^ lr8;
    const u16* gA = HSm + (size_t)(m0 + w * 8 + lr8) * 2048 + lg * 8;
    const u16* gB = Wob + (size_t)(n0 + w * 8 + lr8) * 2048 + lg * 8;

    f32x4 acc[8][4] = {};
    mm256_loop(gA, gB, w, wm, wn, quad, l16, acc);

#pragma unroll
    for (int i = 0; i < 8; i++) {
#pragma unroll
        for (int j = 0; j < 4; j++) {
            int nc = n0 + wn * 64 + j * 16 + l16;
            float bia = bo[nc];
#pragma unroll
            for (int r = 0; r < 4; r++) {
                int mr = m0 + wm * 128 + i * 16 + quad * 4 + r;
                OUT[(size_t)mr * 2048 + nc] = acc[i][j][r] + bia;
            }
        }
    }
}

// ---------------------------------------------------------------------------
extern "C" void kernel_launch(void* const* d_in, const int* in_sizes, int n_in,
                              void* d_out, int out_size, void* d_ws, size_t ws_size,
                              hipStream_t stream) {
    const float* x    = (const float*)d_in[0];
    const float* cosT = (const float*)d_in[1];
    const float* sinT = (const float*)d_in[2];
    const float* Wq   = (const float*)d_in[3];
    const float* bq   = (const float*)d_in[4];
    const float* Wk   = (const float*)d_in[5];
    const float* bk   = (const float*)d_in[6];
    const float* Wv   = (const float*)d_in[7];
    const float* bv   = (const float*)d_in[8];
    const float* Wo   = (const float*)d_in[9];
    const float* bo   = (const float*)d_in[10];

    char* ws = (char*)d_ws;
    u16*   Wqkvb   = (u16*)(ws);                 // 25,165,824 B
    u16*   Wob     = (u16*)(ws + 25165824);      //  8,388,608 B
    u16*   Xb      = (u16*)(ws + 33554432);      // 33,554,432 B (dead after gemm_qkv)
    float* part    = (float*)(ws + 33554432);    // alias Xb: 16,777,216 B
    u16*   V       = (u16*)(ws + 67108864);      // 33,554,432 B
    u16*   HS      = V;                          // V dead after vk_mfma
    u16*   vkb     = (u16*)(ws + 100663296);     //  1,048,576 B (bf16)
    float* ksumbuf = (float*)(ws + 101711872);   //     16,384 B -> ~101.7 MB total

    // Q, K scratch in d_out (exactly 67,108,864 B); dead before gemm_out writes.
    u16* Q  = (u16*)d_out;
    u16* Kb = (u16*)d_out + 16777216;

    hipMemsetAsync(ksumbuf, 0, 32 * 128 * sizeof(float), stream);
    cast_all<<<16384, 256, 0, stream>>>(x, Wq, Wk, Wv, Wo, Xb, Wqkvb, Wob);
    gemm_qkv<<<768, 512, 0, stream>>>(Xb, Wqkvb, bq, bk, bv, cosT, sinT, Q, Kb, V);
    ksum_kernel<<<dim3(32, 8), 256, 0, stream>>>(Kb, ksumbuf);
    vk_mfma<<<dim3(32, 8), 256, 0, stream>>>(Kb, V, part);
    vk_reduce<<<dim3(32, 8), 256, 0, stream>>>(part, vkb);
    hs_mfma<<<dim3(32, 32), 256, 0, stream>>>(Q, vkb, ksumbuf, HS);
    gemm_out<<<256, 512, 0, stream>>>(HS, Wob, bo, (float*)d_out);
}

// Round 4
// 542.715 us; speedup vs baseline: 1.0831x; 1.0052x over previous
//
#include <hip/hip_runtime.h>

// LinearTransformerBlock on MI355X — R9 (= R8 resubmit; container infra failed
// twice last round, no kernel verdict).
// R7 post-mortem: FETCH fixed (438->152 MB) but dur only -35 µs = exactly the
// BW cost of the removed fetch -> the ~6600 cyc/K-tile is intrinsic to the
// schedule, not memory. Diagnosis: P1/P2 issue all 24 ds_reads and lgkmcnt(0)
// them in-phase before MFMA (serializing LDS ~1100-2300 cyc with MFMA 2480
// cyc); P3/P4 are MFMA-only while LDS idles.
// R8/R9: one-phase register lookahead with COUNTED lgkm. P1 reads B+m01+m23,
// waits lgkm(4); P2 reads m45+m67, waits lgkm(8), MFMA m23, trailing lgkm(0)
// (drains m45/m67 under the burst - required before P3's A-restage); P3/P4
// MFMA on resident regs, no lgkm wait. Staging placement + vmcnt ledger
// IDENTICAL to R7 (2 gll16/phase, vmcnt(6) at P4, prologue 14). Hazards:
// B-restage(P2) after B-reads drained (P1 lgkm(4) + barrier); A-restage(P3/P4)
// after A-reads drained (P2 trailing lgkm(0) + barrier). DS retires in-order
// so counted lgkm on pure-DS windows is exact.

typedef unsigned short u16;
typedef __attribute__((ext_vector_type(8))) short bf16x8;
typedef __attribute__((ext_vector_type(4))) float f32x4;

__device__ __forceinline__ float bf2f(u16 u) {
    union { unsigned int i; float f; } x; x.i = ((unsigned int)u) << 16; return x.f;
}
__device__ __forceinline__ u16 f2bf(float f) {
    union { unsigned int i; float f; } x; x.f = f;
    unsigned int i = x.i;
    return (u16)((i + 0x7fffu + ((i >> 16) & 1u)) >> 16);   // RNE
}
__device__ __forceinline__ uint4 pack8(const float* __restrict__ src) {
    float4 f0 = *(const float4*)(src);
    float4 f1 = *(const float4*)(src + 4);
    union { u16 u[8]; uint4 v; } P;
    P.u[0] = f2bf(f0.x); P.u[1] = f2bf(f0.y); P.u[2] = f2bf(f0.z); P.u[3] = f2bf(f0.w);
    P.u[4] = f2bf(f1.x); P.u[5] = f2bf(f1.y); P.u[6] = f2bf(f1.z); P.u[7] = f2bf(f1.w);
    return P.v;
}
__device__ __forceinline__ void gll16(void* lds, const void* g) {
    __builtin_amdgcn_global_load_lds(
        (const __attribute__((address_space(1))) unsigned int*)g,
        (__attribute__((address_space(3))) unsigned int*)lds, 16, 0, 0);
}

// ---------------------------------------------------------------------------
// Kernel 0: one-launch fp32 -> bf16 cast of X, Wq, Wk, Wv, Wo.
// ---------------------------------------------------------------------------
__global__ __launch_bounds__(256) void cast_all(
    const float* __restrict__ x,  const float* __restrict__ Wq,
    const float* __restrict__ Wk, const float* __restrict__ Wv,
    const float* __restrict__ Wo,
    u16* __restrict__ Xb, u16* __restrict__ Wqkvb, u16* __restrict__ Wob)
{
    int bid = blockIdx.x, t = threadIdx.x;
    const float* s; u16* d; size_t i;
    if (bid < 8192)       { s = x;  d = Xb;              i = (size_t)bid * 256 + t; }
    else if (bid < 10240) { s = Wq; d = Wqkvb;           i = (size_t)(bid - 8192)  * 256 + t; }
    else if (bid < 12288) { s = Wk; d = Wqkvb + 4194304; i = (size_t)(bid - 10240) * 256 + t; }
    else if (bid < 14336) { s = Wv; d = Wqkvb + 8388608; i = (size_t)(bid - 12288) * 256 + t; }
    else                  { s = Wo; d = Wob;             i = (size_t)(bid - 14336) * 256 + t; }
    *(uint4*)(d + i * 8) = pack8(s + i * 8);
}

// ---------------------------------------------------------------------------
// 256x256 bf16 MFMA main loop over K=2048 (32 K-tiles of BK=64).
// 8 waves (2M x 4N), per-wave 128x64 output = acc[8][4].
// LDS: A,B each [2 buf][256 rows][64 cols] bf16. XOR swizzle granule^(row&7),
// applied on pre-swizzled global source (staging) and on ds_read address.
// Phase schedule per K-tile t (buf = t&1), lookahead version:
//   P1: ds_read B n0-3 (8) + A m0-1 (4) + A m2-3 (4); stage B23@t+1 -> nbuf;
//       BAR; lgkm(4) [B+m01 ready, m23 in flight]; prio1; MFMA m0-1; prio0; BAR
//   P2: ds_read A m4-5 (4) + m6-7 (4); stage B01@t+2 -> buf; BAR; lgkm(8)
//       [m23 ready]; prio1; MFMA m2-3; prio0; lgkm(0) [drain m45/m67]; BAR
//   P3: stage A01@t+2 -> buf; BAR; prio1; MFMA m4-5 (regs ready); prio0; BAR
//   P4: stage A23@t+2 -> buf; BAR; prio1; MFMA m6-7; prio0; vmcnt(6); BAR
// ---------------------------------------------------------------------------
__device__ __forceinline__ void mm256_loop(
    const u16* __restrict__ gA, const u16* __restrict__ gB,
    int w, int wm, int wn, int quad, int l16,
    f32x4 (&acc)[8][4])
{
    __shared__ __align__(16) u16 As[2 * 16384];
    __shared__ __align__(16) u16 Bs[2 * 16384];

    const size_t CH = 64 * 2048;     // 64-row chunk advance in A/B elements

#define SGA(buf, c, koff) gll16(As + (buf) * 16384 + (c) * 4096 + w * 512, \
                                gA + (size_t)(c) * CH + (koff))
#define SGB(buf, c, koff) gll16(Bs + (buf) * 16384 + (c) * 4096 + w * 512, \
                                gB + (size_t)(c) * CH + (koff))
#define LDA(dst, rowexpr, kk) { int row = (rowexpr); \
    dst = *(const bf16x8*)(Ab + row * 64 + ((((kk << 2) + quad) ^ (row & 7)) << 3)); }
#define LDB(dst, rowexpr, kk) { int row = (rowexpr); \
    dst = *(const bf16x8*)(Bb + row * 64 + ((((kk << 2) + quad) ^ (row & 7)) << 3)); }

    // Prologue: tile0 {A0-3,B0-3}; tile1 {B01, A0-3}.  (14 loads)
    SGA(0, 0, 0); SGA(0, 1, 0); SGA(0, 2, 0); SGA(0, 3, 0);
    SGB(0, 0, 0); SGB(0, 1, 0); SGB(0, 2, 0); SGB(0, 3, 0);
    SGB(1, 0, 64); SGB(1, 1, 64);
    SGA(1, 0, 64); SGA(1, 1, 64); SGA(1, 2, 64); SGA(1, 3, 64);
    asm volatile("s_waitcnt vmcnt(6)" ::: "memory");   // tile0 landed; 6 in flight
    __builtin_amdgcn_s_barrier();

    const u16* A0 = As + wm * 8192;   // wave's 128-row A half
    const u16* B0 = Bs + wn * 4096;   // wave's 64-row B slice

#pragma unroll 2
    for (int t = 0; t < 32; ++t) {
        const int buf = t & 1, nbuf = buf ^ 1;
        const u16* Ab = A0 + buf * 16384;
        const u16* Bb = B0 + buf * 16384;
        const int k1 = (t + 1) * 64, k2 = (t + 2) * 64;

        // ---------------- Phase 1 ----------------
        bf16x8 bF[4][2], a01[2][2], a23[2][2];
#pragma unroll
        for (int n = 0; n < 4; n++)
#pragma unroll
            for (int kk = 0; kk < 2; kk++) LDB(bF[n][kk], n * 16 + l16, kk);
#pragma unroll
        for (int m = 0; m < 2; m++)
#pragma unroll
            for (int kk = 0; kk < 2; kk++) LDA(a01[m][kk], m * 16 + l16, kk);
#pragma unroll
        for (int m = 0; m < 2; m++)
#pragma unroll
            for (int kk = 0; kk < 2; kk++) LDA(a23[m][kk], (m + 2) * 16 + l16, kk);
        if (t < 31) { SGB(nbuf, 2, k1); SGB(nbuf, 3, k1); }
        __builtin_amdgcn_s_barrier();
        asm volatile("s_waitcnt lgkmcnt(4)" ::: "memory");   // B+m01 ready; m23 in flight
        __builtin_amdgcn_s_setprio(1);
#pragma unroll
        for (int m = 0; m < 2; m++)
#pragma unroll
            for (int n = 0; n < 4; n++)
#pragma unroll
                for (int kk = 0; kk < 2; kk++)
                    acc[m][n] = __builtin_amdgcn_mfma_f32_16x16x32_bf16(a01[m][kk], bF[n][kk], acc[m][n], 0, 0, 0);
        __builtin_amdgcn_s_setprio(0);
        __builtin_amdgcn_s_barrier();

        // ---------------- Phase 2 ----------------
        bf16x8 a45[2][2], a67[2][2];
#pragma unroll
        for (int m = 0; m < 2; m++)
#pragma unroll
            for (int kk = 0; kk < 2; kk++) LDA(a45[m][kk], (m + 4) * 16 + l16, kk);
#pragma unroll
        for (int m = 0; m < 2; m++)
#pragma unroll
            for (int kk = 0; kk < 2; kk++) LDA(a67[m][kk], (m + 6) * 16 + l16, kk);
        if (t < 30) { SGB(buf, 0, k2); SGB(buf, 1, k2); }
        __builtin_amdgcn_s_barrier();
        asm volatile("s_waitcnt lgkmcnt(8)" ::: "memory");   // m23 ready; m45/m67 in flight
        __builtin_amdgcn_s_setprio(1);
#pragma unroll
        for (int m = 0; m < 2; m++)
#pragma unroll
            for (int n = 0; n < 4; n++)
#pragma unroll
                for (int kk = 0; kk < 2; kk++)
                    acc[2 + m][n] = __builtin_amdgcn_mfma_f32_16x16x32_bf16(a23[m][kk], bF[n][kk], acc[2 + m][n], 0, 0, 0);
        __builtin_amdgcn_s_setprio(0);
        asm volatile("s_waitcnt lgkmcnt(0)" ::: "memory");   // drain m45/m67 pre-A-restage
        __builtin_amdgcn_s_barrier();

        // ---------------- Phase 3 ----------------
        if (t < 30) { SGA(buf, 0, k2); SGA(buf, 1, k2); }
        __builtin_amdgcn_s_barrier();
        __builtin_amdgcn_s_setprio(1);
#pragma unroll
        for (int m = 0; m < 2; m++)
#pragma unroll
            for (int n = 0; n < 4; n++)
#pragma unroll
                for (int kk = 0; kk < 2; kk++)
                    acc[4 + m][n] = __builtin_amdgcn_mfma_f32_16x16x32_bf16(a45[m][kk], bF[n][kk], acc[4 + m][n], 0, 0, 0);
        __builtin_amdgcn_s_setprio(0);
        __builtin_amdgcn_s_barrier();

        // ---------------- Phase 4 ----------------
        if (t < 30) { SGA(buf, 2, k2); SGA(buf, 3, k2); }
        __builtin_amdgcn_s_barrier();
        __builtin_amdgcn_s_setprio(1);
#pragma unroll
        for (int m = 0; m < 2; m++)
#pragma unroll
            for (int n = 0; n < 4; n++)
#pragma unroll
                for (int kk = 0; kk < 2; kk++)
                    acc[6 + m][n] = __builtin_amdgcn_mfma_f32_16x16x32_bf16(a67[m][kk], bF[n][kk], acc[6 + m][n], 0, 0, 0);
        __builtin_amdgcn_s_setprio(0);
        if (t < 30)       asm volatile("s_waitcnt vmcnt(6)" ::: "memory");
        else if (t == 30) asm volatile("s_waitcnt vmcnt(0)" ::: "memory");
        __builtin_amdgcn_s_barrier();
    }
#undef SGA
#undef SGB
#undef LDA
#undef LDB
}

// ---------------------------------------------------------------------------
// Kernel 1: QKV projection + bias + RoPE + ReLU. 256^2 template.
// Grid remap (R7): XCD x owns A-panels bm ≡ x (mod 8); round r == region r.
// ---------------------------------------------------------------------------
__global__ __launch_bounds__(512, 1) void gemm_qkv(
    const u16* __restrict__ Xb, const u16* __restrict__ Wqkvb,
    const float* __restrict__ bq, const float* __restrict__ bk, const float* __restrict__ bv,
    const float* __restrict__ cosT, const float* __restrict__ sinT,
    u16* __restrict__ Q, u16* __restrict__ K, u16* __restrict__ V)
{
    int t = threadIdx.x, w = t >> 6, lane = t & 63, quad = lane >> 4, l16 = lane & 15;
    int wm = w >> 2, wn = w & 3;

    int bid = blockIdx.x;
    int r = bid >> 8, i = bid & 255, x = i & 7, k = i >> 3;
    int bm = x + ((k & 3) << 3);          // XCD x owns bm ≡ x (mod 8)
    int bn = (r << 3) + (k >> 2);         // round r covers bn ∈ [8r, 8r+8)
    int region = r;                        // == bn >> 3
    const u16*   W    = Wqkvb + (size_t)region * 4194304;
    const float* bias = (region == 0) ? bq : (region == 1 ? bk : bv);
    u16* OUT          = (region == 0) ? Q  : (region == 1 ? K  : V);
    int m0 = bm << 8, n0 = (bn & 7) << 8;

    int lr8 = lane >> 3, lg = (lane & 7) ^ lr8;           // pre-swizzled source granule
    const u16* gA = Xb + (size_t)(m0 + w * 8 + lr8) * 2048 + lg * 8;
    const u16* gB = W  + (size_t)(n0 + w * 8 + lr8) * 2048 + lg * 8;

    f32x4 acc[8][4] = {};
    mm256_loop(gA, gB, w, wm, wn, quad, l16, acc);

#pragma unroll
    for (int i2 = 0; i2 < 8; i2++) {
#pragma unroll
        for (int j = 0; j < 4; j++) {
            int nc   = n0 + wn * 64 + j * 16 + l16;
            int h    = nc >> 7, dpos = nc & 127;
            float bia = bias[nc];
#pragma unroll
            for (int rr = 0; rr < 4; rr++) {
                int mr = m0 + wm * 128 + i2 * 16 + quad * 4 + rr;   // C/D: row = quad*4+reg
                int b  = mr >> 12, s = mr & 4095;
                float val = acc[i2][j][rr] + bia;
                if (region < 2) {
                    float pair = __shfl_xor(val, 1, 64);
                    float c  = cosT[s * 128 + dpos];
                    float sn = sinT[s * 128 + dpos];
                    val = fmaxf(val * c + ((dpos & 1) ? pair : -pair) * sn, 0.f);
                }
                OUT[((size_t)(b * 16 + h) * 4096 + s) * 128 + dpos] = f2bf(val);
            }
        }
    }
}

// ---------------------------------------------------------------------------
// Kernel 2: ksum[bh][d] = sum_s K[bh][s][d]  (atomic partial per 512-s block).
// ---------------------------------------------------------------------------
__global__ __launch_bounds__(256) void ksum_kernel(
    const u16* __restrict__ Kb, float* __restrict__ ksumbuf)
{
    int bh = blockIdx.x, sc8 = blockIdx.y, t = threadIdx.x;
    int dpair = (t & 63) * 2, sq = t >> 6;
    const u16* base = Kb + (size_t)bh * 524288 + (size_t)(sc8 * 512 + sq * 128) * 128 + dpair;
    float s0 = 0.f, s1 = 0.f;
#pragma unroll 8
    for (int r = 0; r < 128; r++) {
        unsigned int wv = *(const unsigned int*)(base + (size_t)r * 128);
        s0 += bf2f((u16)(wv & 0xffff));
        s1 += bf2f((u16)(wv >> 16));
    }
    __shared__ float red[4][128];
    red[sq][dpair]     = s0;
    red[sq][dpair + 1] = s1;
    __syncthreads();
    if (t < 128) {
        float tot = red[0][t] + red[1][t] + red[2][t] + red[3][t];
        atomicAdd(&ksumbuf[bh * 128 + t], tot);
    }
}

// ---------------------------------------------------------------------------
// Kernel 3: vk partials via MFMA. Per (bh, sk): C[128n][128d] = sum_s V[s,n]K[s,d]
// over 512 s. Operands staged transposed into LDS (swizzled).
// ---------------------------------------------------------------------------
__global__ __launch_bounds__(256) void vk_mfma(
    const u16* __restrict__ Kb, const u16* __restrict__ Vb, float* __restrict__ part)
{
    int bh = blockIdx.x;          // 0..31
    int sk = blockIdx.y;          // 0..7
    int t  = threadIdx.x;
    int s0 = sk * 512;

    __shared__ __align__(16) u16 Kt[128 * 32];
    __shared__ __align__(16) u16 Vt[128 * 32];

    const u16* Kp = Kb + (size_t)bh * 524288;
    const u16* Vp = Vb + (size_t)bh * 524288;

    int dgrp  = t & 15;
    int d0    = dgrp * 8;
    int spair = (t >> 4) * 2;
    int sg    = spair >> 3;

    int w = t >> 6, lane = t & 63, quad = lane >> 4, l16 = lane & 15;
    int nbase = (w >> 1) * 64, dbase = (w & 1) * 64;

    f32x4 acc[4][4] = {};

    for (int tile = 0; tile < 16; tile++) {
        int st = s0 + tile * 32;
        __syncthreads();
        {
            const u16* kg = Kp + (size_t)(st + spair) * 128 + d0;
            const u16* vg = Vp + (size_t)(st + spair) * 128 + d0;
            union { uint4 v; u16 u[8]; } ka, kb, va, vb;
            ka.v = *(const uint4*)kg;  kb.v = *(const uint4*)(kg + 128);
            va.v = *(const uint4*)vg;  vb.v = *(const uint4*)(vg + 128);
            int swz = (((sg + dgrp) & 3) << 3) + (spair & 7);
#pragma unroll
            for (int i = 0; i < 8; i++) {
                int e = (d0 + i) * 32 + swz;
                *(unsigned int*)(Kt + e) = (unsigned int)ka.u[i] | ((unsigned int)kb.u[i] << 16);
                *(unsigned int*)(Vt + e) = (unsigned int)va.u[i] | ((unsigned int)vb.u[i] << 16);
            }
        }
        __syncthreads();

        bf16x8 af[4], bfr[4];
#pragma unroll
        for (int i = 0; i < 4; i++) {
            int r = nbase + i * 16 + l16;
            af[i] = *(const bf16x8*)(Vt + r * 32 + (((quad + (r >> 3)) & 3) << 3));
        }
#pragma unroll
        for (int j = 0; j < 4; j++) {
            int r = dbase + j * 16 + l16;
            bfr[j] = *(const bf16x8*)(Kt + r * 32 + (((quad + (r >> 3)) & 3) << 3));
        }
#pragma unroll
        for (int i = 0; i < 4; i++)
#pragma unroll
            for (int j = 0; j < 4; j++)
                acc[i][j] = __builtin_amdgcn_mfma_f32_16x16x32_bf16(af[i], bfr[j], acc[i][j], 0, 0, 0);
    }

    float* dst = part + (size_t)(bh * 8 + sk) * 16384;
#pragma unroll
    for (int i = 0; i < 4; i++) {
#pragma unroll
        for (int j = 0; j < 4; j++) {
#pragma unroll
            for (int r = 0; r < 4; r++) {
                int n = nbase + i * 16 + quad * 4 + r;
                int d = dbase + j * 16 + l16;
                dst[n * 128 + d] = acc[i][j][r];
            }
        }
    }
}

// ---------------------------------------------------------------------------
// Kernel 4: reduce 8 partials -> vkb[32][128*128] bf16 (hs consumes bf16).
// ---------------------------------------------------------------------------
__global__ __launch_bounds__(256) void vk_reduce(const float* __restrict__ part,
                                                 u16* __restrict__ vkb)
{
    int bh = blockIdx.x, by = blockIdx.y, t = threadIdx.x;
    int end = (by + 1) * 2048;
    for (int idx = by * 2048 + t; idx < end; idx += 256) {
        float s = 0.f;
#pragma unroll
        for (int p = 0; p < 8; p++) s += part[(size_t)(bh * 8 + p) * 16384 + idx];
        vkb[(size_t)bh * 16384 + idx] = f2bf(s);
    }
}

// ---------------------------------------------------------------------------
// Kernel 5: hs via MFMA, denominator fused. Per (bh, sc):
// hs[128s,128n] = (q @ vk^T) * rden, rden = 1/(q . ksum + eps). vk is bf16.
// ---------------------------------------------------------------------------
__global__ __launch_bounds__(256) void hs_mfma(
    const u16* __restrict__ Qb, const u16* __restrict__ vkb,
    const float* __restrict__ ksumbuf, u16* __restrict__ HS)
{
    int bh = blockIdx.x, sc = blockIdx.y;
    __shared__ __align__(16) u16 qL[128 * 136];
    __shared__ __align__(16) u16 vkL[128 * 136];
    __shared__ float rdL[128];
    __shared__ float ksumL[128];
    int t = threadIdx.x;

    const u16* Qp   = Qb  + ((size_t)bh * 4096 + sc * 128) * 128;
    const u16* vsrc = vkb + (size_t)bh * 16384;
    int row = t >> 4, colc = (t & 15) * 8;
#pragma unroll
    for (int r8 = 0; r8 < 8; r8++) {
        int rr = row + r8 * 16;
        *(uint4*)(qL  + rr * 136 + colc) = *(const uint4*)(Qp   + (size_t)rr * 128 + colc);
        *(uint4*)(vkL + rr * 136 + colc) = *(const uint4*)(vsrc + (size_t)rr * 128 + colc);
    }
    if (t < 128) ksumL[t] = ksumbuf[bh * 128 + t];
    __syncthreads();

    // Fused denominator: thread pair (srow, half).
    {
        int srow = t >> 1, half = t & 1;
        const u16*   q  = qL + srow * 136 + half * 64;
        const float* kp = ksumL + half * 64;
        float p = 0.f;
#pragma unroll 8
        for (int d = 0; d < 64; d += 4) {
            ushort4 qv = *(const ushort4*)(q + d);
            p += bf2f(qv.x) * kp[d] + bf2f(qv.y) * kp[d + 1]
               + bf2f(qv.z) * kp[d + 2] + bf2f(qv.w) * kp[d + 3];
        }
        p += __shfl_xor(p, 1, 64);
        if (half == 0) rdL[srow] = 1.0f / (p + 1e-15f);
    }

    int w = t >> 6, lane = t & 63, quad = lane >> 4, l16 = lane & 15;
    int wm0 = (w >> 1) * 64, wn0 = (w & 1) * 64;
    f32x4 acc[4][4] = {};
#pragma unroll
    for (int ks = 0; ks < 4; ks++) {
        bf16x8 af[4], bfr[4];
#pragma unroll
        for (int i = 0; i < 4; i++) af[i]  = *(const bf16x8*)(qL  + (wm0 + i * 16 + l16) * 136 + ks * 32 + quad * 8);
#pragma unroll
        for (int j = 0; j < 4; j++) bfr[j] = *(const bf16x8*)(vkL + (wn0 + j * 16 + l16) * 136 + ks * 32 + quad * 8);
#pragma unroll
        for (int i = 0; i < 4; i++)
#pragma unroll
            for (int j = 0; j < 4; j++)
                acc[i][j] = __builtin_amdgcn_mfma_f32_16x16x32_bf16(af[i], bfr[j], acc[i][j], 0, 0, 0);
    }
    __syncthreads();   // rdL ready

    int b = bh >> 4, h = bh & 15;
#pragma unroll
    for (int i = 0; i < 4; i++) {
#pragma unroll
        for (int j = 0; j < 4; j++) {
#pragma unroll
            for (int r = 0; r < 4; r++) {
                int sl = wm0 + i * 16 + quad * 4 + r;
                int n  = wn0 + j * 16 + l16;
                size_t srow = (size_t)b * 4096 + sc * 128 + sl;
                HS[srow * 2048 + h * 128 + n] = f2bf(acc[i][j][r] * rdL[sl]);
            }
        }
    }
}

// ---------------------------------------------------------------------------
// Kernel 6: out = HS @ Wo^T + bo, 256^2 template, fp32 out.
// Grid remap (R7): XCD x owns bm ≡ x (mod 8); bn = k>>2. Bijective.
// ---------------------------------------------------------------------------
__global__ __launch_bounds__(512, 1) void gemm_out(
    const u16* __restrict__ HSm, const u16* __restrict__ Wob,
    const float* __restrict__ bo, float* __restrict__ OUT)
{
    int t = threadIdx.x, w = t >> 6, lane = t & 63, quad = lane >> 4, l16 = lane & 15;
    int wm = w >> 2, wn = w & 3;

    int x = blockIdx.x & 7, k = blockIdx.x >> 3;
    int bm = x + ((k & 3) << 3);          // XCD x owns bm ≡ x (mod 8)
    int bn = k >> 2;
    int m0 = bm << 8, n0 = bn << 8;

    int lr8 = lane >> 3, lg = (lane & 7) ^ lr8;
    const u16* gA = HSm + (size_t)(m0 + w * 8 + lr8) * 2048 + lg * 8;
    const u16* gB = Wob + (size_t)(n0 + w * 8 + lr8) * 2048 + lg * 8;

    f32x4 acc[8][4] = {};
    mm256_loop(gA, gB, w, wm, wn, quad, l16, acc);

#pragma unroll
    for (int i = 0; i < 8; i++) {
#pragma unroll
        for (int j = 0; j < 4; j++) {
            int nc = n0 + wn * 64 + j * 16 + l16;
            float bia = bo[nc];
#pragma unroll
            for (int r = 0; r < 4; r++) {
                int mr = m0 + wm * 128 + i * 16 + quad * 4 + r;
                OUT[(size_t)mr * 2048 + nc] = acc[i][j][r] + bia;
            }
        }
    }
}

// ---------------------------------------------------------------------------
extern "C" void kernel_launch(void* const* d_in, const int* in_sizes, int n_in,
                              void* d_out, int out_size, void* d_ws, size_t ws_size,
                              hipStream_t stream) {
    const float* x    = (const float*)d_in[0];
    const float* cosT = (const float*)d_in[1];
    const float* sinT = (const float*)d_in[2];
    const float* Wq   = (const float*)d_in[3];
    const float* bq   = (const float*)d_in[4];
    const float* Wk   = (const float*)d_in[5];
    const float* bk   = (const float*)d_in[6];
    const float* Wv   = (const float*)d_in[7];
    const float* bv   = (const float*)d_in[8];
    const float* Wo   = (const float*)d_in[9];
    const float* bo   = (const float*)d_in[10];

    char* ws = (char*)d_ws;
    u16*   Wqkvb   = (u16*)(ws);                 // 25,165,824 B
    u16*   Wob     = (u16*)(ws + 25165824);      //  8,388,608 B
    u16*   Xb      = (u16*)(ws + 33554432);      // 33,554,432 B (dead after gemm_qkv)
    float* part    = (float*)(ws + 33554432);    // alias Xb: 16,777,216 B
    u16*   V       = (u16*)(ws + 67108864);      // 33,554,432 B
    u16*   HS      = V;                          // V dead after vk_mfma
    u16*   vkb     = (u16*)(ws + 100663296);     //  1,048,576 B (bf16)
    float* ksumbuf = (float*)(ws + 101711872);   //     16,384 B -> ~101.7 MB total

    // Q, K scratch in d_out (exactly 67,108,864 B); dead before gemm_out writes.
    u16* Q  = (u16*)d_out;
    u16* Kb = (u16*)d_out + 16777216;

    hipMemsetAsync(ksumbuf, 0, 32 * 128 * sizeof(float), stream);
    cast_all<<<16384, 256, 0, stream>>>(x, Wq, Wk, Wv, Wo, Xb, Wqkvb, Wob);
    gemm_qkv<<<768, 512, 0, stream>>>(Xb, Wqkvb, bq, bk, bv, cosT, sinT, Q, Kb, V);
    ksum_kernel<<<dim3(32, 8), 256, 0, stream>>>(Kb, ksumbuf);
    vk_mfma<<<dim3(32, 8), 256, 0, stream>>>(Kb, V, part);
    vk_reduce<<<dim3(32, 8), 256, 0, stream>>>(part, vkb);
    hs_mfma<<<dim3(32, 32), 256, 0, stream>>>(Q, vkb, ksumbuf, HS);
    gemm_out<<<256, 512, 0, stream>>>(HS, Wob, bo, (float*)d_out);
}

// Round 6
// 538.763 us; speedup vs baseline: 1.0910x; 1.0073x over previous
//
#include <hip/hip_runtime.h>

// LinearTransformerBlock on MI355X — R11 (= R10 resubmit; container infra
// failed twice, no kernel verdict; R8 precedent: identical source passed on
// resubmit).
// R9 post-mortem: counted-lgkm lookahead = NULL (275.9 vs R7 278.5). Nothing
// saturated (HBM 12%, LDS 11%, Mfma 31%, VALU 18%, Occ 22%); occupancy is
// register-capped at 2 waves/SIMD. Latency-bound; untested shared cost is
// 8 x 8-wave s_barrier per K-tile (~1000-1600 cyc lockstep + no cross-phase
// scheduling).
// R10/R11: SINGLE-barrier K-tile. Hazard proof: reads(t-1) drained per-wave by
// lgkm ladder before end-of-tile barrier; stages(t+1->nbuf) issue after it;
// vmcnt(0) before the barrier publishes t+1 (gll16 counts vmcnt only; DS
// retires in-order so counted lgkm over pure-ds windows is exact). Ladder:
// issue B(8),a01..a67(16) + 8 gll16, then lgkm(12) MFMA m01, lgkm(8) m23,
// lgkm(4) m45, lgkm(0) m67, vmcnt(0), s_barrier. Swizzle/remap/epilogues
// unchanged from R9.

typedef unsigned short u16;
typedef __attribute__((ext_vector_type(8))) short bf16x8;
typedef __attribute__((ext_vector_type(4))) float f32x4;

__device__ __forceinline__ float bf2f(u16 u) {
    union { unsigned int i; float f; } x; x.i = ((unsigned int)u) << 16; return x.f;
}
__device__ __forceinline__ u16 f2bf(float f) {
    union { unsigned int i; float f; } x; x.f = f;
    unsigned int i = x.i;
    return (u16)((i + 0x7fffu + ((i >> 16) & 1u)) >> 16);   // RNE
}
__device__ __forceinline__ uint4 pack8(const float* __restrict__ src) {
    float4 f0 = *(const float4*)(src);
    float4 f1 = *(const float4*)(src + 4);
    union { u16 u[8]; uint4 v; } P;
    P.u[0] = f2bf(f0.x); P.u[1] = f2bf(f0.y); P.u[2] = f2bf(f0.z); P.u[3] = f2bf(f0.w);
    P.u[4] = f2bf(f1.x); P.u[5] = f2bf(f1.y); P.u[6] = f2bf(f1.z); P.u[7] = f2bf(f1.w);
    return P.v;
}
__device__ __forceinline__ void gll16(void* lds, const void* g) {
    __builtin_amdgcn_global_load_lds(
        (const __attribute__((address_space(1))) unsigned int*)g,
        (__attribute__((address_space(3))) unsigned int*)lds, 16, 0, 0);
}

// ---------------------------------------------------------------------------
// Kernel 0: one-launch fp32 -> bf16 cast of X, Wq, Wk, Wv, Wo.
// ---------------------------------------------------------------------------
__global__ __launch_bounds__(256) void cast_all(
    const float* __restrict__ x,  const float* __restrict__ Wq,
    const float* __restrict__ Wk, const float* __restrict__ Wv,
    const float* __restrict__ Wo,
    u16* __restrict__ Xb, u16* __restrict__ Wqkvb, u16* __restrict__ Wob)
{
    int bid = blockIdx.x, t = threadIdx.x;
    const float* s; u16* d; size_t i;
    if (bid < 8192)       { s = x;  d = Xb;              i = (size_t)bid * 256 + t; }
    else if (bid < 10240) { s = Wq; d = Wqkvb;           i = (size_t)(bid - 8192)  * 256 + t; }
    else if (bid < 12288) { s = Wk; d = Wqkvb + 4194304; i = (size_t)(bid - 10240) * 256 + t; }
    else if (bid < 14336) { s = Wv; d = Wqkvb + 8388608; i = (size_t)(bid - 12288) * 256 + t; }
    else                  { s = Wo; d = Wob;             i = (size_t)(bid - 14336) * 256 + t; }
    *(uint4*)(d + i * 8) = pack8(s + i * 8);
}

// ---------------------------------------------------------------------------
// 256x256 bf16 MFMA main loop over K=2048 (32 K-tiles of BK=64).
// 8 waves (2M x 4N), per-wave 128x64 output = acc[8][4].
// LDS: A,B each [2 buf][256 rows][64 cols] bf16. XOR swizzle granule^(row&7),
// applied on pre-swizzled global source (staging) and on ds_read address.
// R10/R11 single-barrier tile (see header). In-flight vmem during tile t: the
// 8 gll16 of tile t+1, drained by vmcnt(0) at tile end (cover = whole tile).
// ---------------------------------------------------------------------------
__device__ __forceinline__ void mm256_loop(
    const u16* __restrict__ gA, const u16* __restrict__ gB,
    int w, int wm, int wn, int quad, int l16,
    f32x4 (&acc)[8][4])
{
    __shared__ __align__(16) u16 As[2 * 16384];
    __shared__ __align__(16) u16 Bs[2 * 16384];

    const size_t CH = 64 * 2048;     // 64-row chunk advance in A/B elements

#define SGA(buf, c, koff) gll16(As + (buf) * 16384 + (c) * 4096 + w * 512, \
                                gA + (size_t)(c) * CH + (koff))
#define SGB(buf, c, koff) gll16(Bs + (buf) * 16384 + (c) * 4096 + w * 512, \
                                gB + (size_t)(c) * CH + (koff))
#define LDA(dst, rowexpr, kk) { int row = (rowexpr); \
    dst = *(const bf16x8*)(Ab + row * 64 + ((((kk << 2) + quad) ^ (row & 7)) << 3)); }
#define LDB(dst, rowexpr, kk) { int row = (rowexpr); \
    dst = *(const bf16x8*)(Bb + row * 64 + ((((kk << 2) + quad) ^ (row & 7)) << 3)); }

    // Prologue: stage tile0 only; steady loop stages t+1 during t.
    SGA(0, 0, 0); SGA(0, 1, 0); SGA(0, 2, 0); SGA(0, 3, 0);
    SGB(0, 0, 0); SGB(0, 1, 0); SGB(0, 2, 0); SGB(0, 3, 0);
    asm volatile("s_waitcnt vmcnt(0)" ::: "memory");
    __builtin_amdgcn_s_barrier();

    const u16* A0 = As + wm * 8192;   // wave's 128-row A half
    const u16* B0 = Bs + wn * 4096;   // wave's 64-row B slice

#pragma unroll 2
    for (int t = 0; t < 32; ++t) {
        const int buf = t & 1, nbuf = buf ^ 1;
        const u16* Ab = A0 + buf * 16384;
        const u16* Bb = B0 + buf * 16384;
        const int k1 = (t + 1) * 64;

        // --- issue all 24 ds_reads in ladder order: B(8), a01, a23, a45, a67
        bf16x8 bF[4][2], aA[8][2];
#pragma unroll
        for (int n = 0; n < 4; n++)
#pragma unroll
            for (int kk = 0; kk < 2; kk++) LDB(bF[n][kk], n * 16 + l16, kk);
#pragma unroll
        for (int m = 0; m < 8; m++)
#pragma unroll
            for (int kk = 0; kk < 2; kk++) LDA(aA[m][kk], m * 16 + l16, kk);

        // --- issue all 8 stages for tile t+1 into nbuf
        if (t < 31) {
            SGB(nbuf, 0, k1); SGB(nbuf, 1, k1); SGB(nbuf, 2, k1); SGB(nbuf, 3, k1);
            SGA(nbuf, 0, k1); SGA(nbuf, 1, k1); SGA(nbuf, 2, k1); SGA(nbuf, 3, k1);
        }

        // --- counted lgkm ladder + MFMA (compiler's own dep-waits guarantee
        //     correctness; the ladder shapes the overlap)
        asm volatile("s_waitcnt lgkmcnt(12)" ::: "memory");   // B + a01 ready
        __builtin_amdgcn_s_setprio(1);
#pragma unroll
        for (int m = 0; m < 2; m++)
#pragma unroll
            for (int n = 0; n < 4; n++)
#pragma unroll
                for (int kk = 0; kk < 2; kk++)
                    acc[m][n] = __builtin_amdgcn_mfma_f32_16x16x32_bf16(aA[m][kk], bF[n][kk], acc[m][n], 0, 0, 0);
        asm volatile("s_waitcnt lgkmcnt(8)" ::: "memory");    // a23 ready
#pragma unroll
        for (int m = 2; m < 4; m++)
#pragma unroll
            for (int n = 0; n < 4; n++)
#pragma unroll
                for (int kk = 0; kk < 2; kk++)
                    acc[m][n] = __builtin_amdgcn_mfma_f32_16x16x32_bf16(aA[m][kk], bF[n][kk], acc[m][n], 0, 0, 0);
        asm volatile("s_waitcnt lgkmcnt(4)" ::: "memory");    // a45 ready
#pragma unroll
        for (int m = 4; m < 6; m++)
#pragma unroll
            for (int n = 0; n < 4; n++)
#pragma unroll
                for (int kk = 0; kk < 2; kk++)
                    acc[m][n] = __builtin_amdgcn_mfma_f32_16x16x32_bf16(aA[m][kk], bF[n][kk], acc[m][n], 0, 0, 0);
        asm volatile("s_waitcnt lgkmcnt(0)" ::: "memory");    // a67 ready
#pragma unroll
        for (int m = 6; m < 8; m++)
#pragma unroll
            for (int n = 0; n < 4; n++)
#pragma unroll
                for (int kk = 0; kk < 2; kk++)
                    acc[m][n] = __builtin_amdgcn_mfma_f32_16x16x32_bf16(aA[m][kk], bF[n][kk], acc[m][n], 0, 0, 0);
        __builtin_amdgcn_s_setprio(0);

        // --- publish tile t+1, single barrier
        asm volatile("s_waitcnt vmcnt(0)" ::: "memory");
        __builtin_amdgcn_s_barrier();
    }
#undef SGA
#undef SGB
#undef LDA
#undef LDB
}

// ---------------------------------------------------------------------------
// Kernel 1: QKV projection + bias + RoPE + ReLU. 256^2 template.
// Grid remap (R7): XCD x owns A-panels bm ≡ x (mod 8); round r == region r.
// ---------------------------------------------------------------------------
__global__ __launch_bounds__(512, 1) void gemm_qkv(
    const u16* __restrict__ Xb, const u16* __restrict__ Wqkvb,
    const float* __restrict__ bq, const float* __restrict__ bk, const float* __restrict__ bv,
    const float* __restrict__ cosT, const float* __restrict__ sinT,
    u16* __restrict__ Q, u16* __restrict__ K, u16* __restrict__ V)
{
    int t = threadIdx.x, w = t >> 6, lane = t & 63, quad = lane >> 4, l16 = lane & 15;
    int wm = w >> 2, wn = w & 3;

    int bid = blockIdx.x;
    int r = bid >> 8, i = bid & 255, x = i & 7, k = i >> 3;
    int bm = x + ((k & 3) << 3);          // XCD x owns bm ≡ x (mod 8)
    int bn = (r << 3) + (k >> 2);         // round r covers bn ∈ [8r, 8r+8)
    int region = r;                        // == bn >> 3
    const u16*   W    = Wqkvb + (size_t)region * 4194304;
    const float* bias = (region == 0) ? bq : (region == 1 ? bk : bv);
    u16* OUT          = (region == 0) ? Q  : (region == 1 ? K  : V);
    int m0 = bm << 8, n0 = (bn & 7) << 8;

    int lr8 = lane >> 3, lg = (lane & 7) ^ lr8;           // pre-swizzled source granule
    const u16* gA = Xb + (size_t)(m0 + w * 8 + lr8) * 2048 + lg * 8;
    const u16* gB = W  + (size_t)(n0 + w * 8 + lr8) * 2048 + lg * 8;

    f32x4 acc[8][4] = {};
    mm256_loop(gA, gB, w, wm, wn, quad, l16, acc);

#pragma unroll
    for (int i2 = 0; i2 < 8; i2++) {
#pragma unroll
        for (int j = 0; j < 4; j++) {
            int nc   = n0 + wn * 64 + j * 16 + l16;
            int h    = nc >> 7, dpos = nc & 127;
            float bia = bias[nc];
#pragma unroll
            for (int rr = 0; rr < 4; rr++) {
                int mr = m0 + wm * 128 + i2 * 16 + quad * 4 + rr;   // C/D: row = quad*4+reg
                int b  = mr >> 12, s = mr & 4095;
                float val = acc[i2][j][rr] + bia;
                if (region < 2) {
                    float pair = __shfl_xor(val, 1, 64);
                    float c  = cosT[s * 128 + dpos];
                    float sn = sinT[s * 128 + dpos];
                    val = fmaxf(val * c + ((dpos & 1) ? pair : -pair) * sn, 0.f);
                }
                OUT[((size_t)(b * 16 + h) * 4096 + s) * 128 + dpos] = f2bf(val);
            }
        }
    }
}

// ---------------------------------------------------------------------------
// Kernel 2: ksum[bh][d] = sum_s K[bh][s][d]  (atomic partial per 512-s block).
// ---------------------------------------------------------------------------
__global__ __launch_bounds__(256) void ksum_kernel(
    const u16* __restrict__ Kb, float* __restrict__ ksumbuf)
{
    int bh = blockIdx.x, sc8 = blockIdx.y, t = threadIdx.x;
    int dpair = (t & 63) * 2, sq = t >> 6;
    const u16* base = Kb + (size_t)bh * 524288 + (size_t)(sc8 * 512 + sq * 128) * 128 + dpair;
    float s0 = 0.f, s1 = 0.f;
#pragma unroll 8
    for (int r = 0; r < 128; r++) {
        unsigned int wv = *(const unsigned int*)(base + (size_t)r * 128);
        s0 += bf2f((u16)(wv & 0xffff));
        s1 += bf2f((u16)(wv >> 16));
    }
    __shared__ float red[4][128];
    red[sq][dpair]     = s0;
    red[sq][dpair + 1] = s1;
    __syncthreads();
    if (t < 128) {
        float tot = red[0][t] + red[1][t] + red[2][t] + red[3][t];
        atomicAdd(&ksumbuf[bh * 128 + t], tot);
    }
}

// ---------------------------------------------------------------------------
// Kernel 3: vk partials via MFMA. Per (bh, sk): C[128n][128d] = sum_s V[s,n]K[s,d]
// over 512 s. Operands staged transposed into LDS (swizzled).
// ---------------------------------------------------------------------------
__global__ __launch_bounds__(256) void vk_mfma(
    const u16* __restrict__ Kb, const u16* __restrict__ Vb, float* __restrict__ part)
{
    int bh = blockIdx.x;          // 0..31
    int sk = blockIdx.y;          // 0..7
    int t  = threadIdx.x;
    int s0 = sk * 512;

    __shared__ __align__(16) u16 Kt[128 * 32];
    __shared__ __align__(16) u16 Vt[128 * 32];

    const u16* Kp = Kb + (size_t)bh * 524288;
    const u16* Vp = Vb + (size_t)bh * 524288;

    int dgrp  = t & 15;
    int d0    = dgrp * 8;
    int spair = (t >> 4) * 2;
    int sg    = spair >> 3;

    int w = t >> 6, lane = t & 63, quad = lane >> 4, l16 = lane & 15;
    int nbase = (w >> 1) * 64, dbase = (w & 1) * 64;

    f32x4 acc[4][4] = {};

    for (int tile = 0; tile < 16; tile++) {
        int st = s0 + tile * 32;
        __syncthreads();
        {
            const u16* kg = Kp + (size_t)(st + spair) * 128 + d0;
            const u16* vg = Vp + (size_t)(st + spair) * 128 + d0;
            union { uint4 v; u16 u[8]; } ka, kb, va, vb;
            ka.v = *(const uint4*)kg;  kb.v = *(const uint4*)(kg + 128);
            va.v = *(const uint4*)vg;  vb.v = *(const uint4*)(vg + 128);
            int swz = (((sg + dgrp) & 3) << 3) + (spair & 7);
#pragma unroll
            for (int i = 0; i < 8; i++) {
                int e = (d0 + i) * 32 + swz;
                *(unsigned int*)(Kt + e) = (unsigned int)ka.u[i] | ((unsigned int)kb.u[i] << 16);
                *(unsigned int*)(Vt + e) = (unsigned int)va.u[i] | ((unsigned int)vb.u[i] << 16);
            }
        }
        __syncthreads();

        bf16x8 af[4], bfr[4];
#pragma unroll
        for (int i = 0; i < 4; i++) {
            int r = nbase + i * 16 + l16;
            af[i] = *(const bf16x8*)(Vt + r * 32 + (((quad + (r >> 3)) & 3) << 3));
        }
#pragma unroll
        for (int j = 0; j < 4; j++) {
            int r = dbase + j * 16 + l16;
            bfr[j] = *(const bf16x8*)(Kt + r * 32 + (((quad + (r >> 3)) & 3) << 3));
        }
#pragma unroll
        for (int i = 0; i < 4; i++)
#pragma unroll
            for (int j = 0; j < 4; j++)
                acc[i][j] = __builtin_amdgcn_mfma_f32_16x16x32_bf16(af[i], bfr[j], acc[i][j], 0, 0, 0);
    }

    float* dst = part + (size_t)(bh * 8 + sk) * 16384;
#pragma unroll
    for (int i = 0; i < 4; i++) {
#pragma unroll
        for (int j = 0; j < 4; j++) {
#pragma unroll
            for (int r = 0; r < 4; r++) {
                int n = nbase + i * 16 + quad * 4 + r;
                int d = dbase + j * 16 + l16;
                dst[n * 128 + d] = acc[i][j][r];
            }
        }
    }
}

// ---------------------------------------------------------------------------
// Kernel 4: reduce 8 partials -> vkb[32][128*128] bf16 (hs consumes bf16).
// ---------------------------------------------------------------------------
__global__ __launch_bounds__(256) void vk_reduce(const float* __restrict__ part,
                                                 u16* __restrict__ vkb)
{
    int bh = blockIdx.x, by = blockIdx.y, t = threadIdx.x;
    int end = (by + 1) * 2048;
    for (int idx = by * 2048 + t; idx < end; idx += 256) {
        float s = 0.f;
#pragma unroll
        for (int p = 0; p < 8; p++) s += part[(size_t)(bh * 8 + p) * 16384 + idx];
        vkb[(size_t)bh * 16384 + idx] = f2bf(s);
    }
}

// ---------------------------------------------------------------------------
// Kernel 5: hs via MFMA, denominator fused. Per (bh, sc):
// hs[128s,128n] = (q @ vk^T) * rden, rden = 1/(q . ksum + eps). vk is bf16.
// ---------------------------------------------------------------------------
__global__ __launch_bounds__(256) void hs_mfma(
    const u16* __restrict__ Qb, const u16* __restrict__ vkb,
    const float* __restrict__ ksumbuf, u16* __restrict__ HS)
{
    int bh = blockIdx.x, sc = blockIdx.y;
    __shared__ __align__(16) u16 qL[128 * 136];
    __shared__ __align__(16) u16 vkL[128 * 136];
    __shared__ float rdL[128];
    __shared__ float ksumL[128];
    int t = threadIdx.x;

    const u16* Qp   = Qb  + ((size_t)bh * 4096 + sc * 128) * 128;
    const u16* vsrc = vkb + (size_t)bh * 16384;
    int row = t >> 4, colc = (t & 15) * 8;
#pragma unroll
    for (int r8 = 0; r8 < 8; r8++) {
        int rr = row + r8 * 16;
        *(uint4*)(qL  + rr * 136 + colc) = *(const uint4*)(Qp   + (size_t)rr * 128 + colc);
        *(uint4*)(vkL + rr * 136 + colc) = *(const uint4*)(vsrc + (size_t)rr * 128 + colc);
    }
    if (t < 128) ksumL[t] = ksumbuf[bh * 128 + t];
    __syncthreads();

    // Fused denominator: thread pair (srow, half).
    {
        int srow = t >> 1, half = t & 1;
        const u16*   q  = qL + srow * 136 + half * 64;
        const float* kp = ksumL + half * 64;
        float p = 0.f;
#pragma unroll 8
        for (int d = 0; d < 64; d += 4) {
            ushort4 qv = *(const ushort4*)(q + d);
            p += bf2f(qv.x) * kp[d] + bf2f(qv.y) * kp[d + 1]
               + bf2f(qv.z) * kp[d + 2] + bf2f(qv.w) * kp[d + 3];
        }
        p += __shfl_xor(p, 1, 64);
        if (half == 0) rdL[srow] = 1.0f / (p + 1e-15f);
    }

    int w = t >> 6, lane = t & 63, quad = lane >> 4, l16 = lane & 15;
    int wm0 = (w >> 1) * 64, wn0 = (w & 1) * 64;
    f32x4 acc[4][4] = {};
#pragma unroll
    for (int ks = 0; ks < 4; ks++) {
        bf16x8 af[4], bfr[4];
#pragma unroll
        for (int i = 0; i < 4; i++) af[i]  = *(const bf16x8*)(qL  + (wm0 + i * 16 + l16) * 136 + ks * 32 + quad * 8);
#pragma unroll
        for (int j = 0; j < 4; j++) bfr[j] = *(const bf16x8*)(vkL + (wn0 + j * 16 + l16) * 136 + ks * 32 + quad * 8);
#pragma unroll
        for (int i = 0; i < 4; i++)
#pragma unroll
            for (int j = 0; j < 4; j++)
                acc[i][j] = __builtin_amdgcn_mfma_f32_16x16x32_bf16(af[i], bfr[j], acc[i][j], 0, 0, 0);
    }
    __syncthreads();   // rdL ready

    int b = bh >> 4, h = bh & 15;
#pragma unroll
    for (int i = 0; i < 4; i++) {
#pragma unroll
        for (int j = 0; j < 4; j++) {
#pragma unroll
            for (int r = 0; r < 4; r++) {
                int sl = wm0 + i * 16 + quad * 4 + r;
                int n  = wn0 + j * 16 + l16;
                size_t srow = (size_t)b * 4096 + sc * 128 + sl;
                HS[srow * 2048 + h * 128 + n] = f2bf(acc[i][j][r] * rdL[sl]);
            }
        }
    }
}

// ---------------------------------------------------------------------------
// Kernel 6: out = HS @ Wo^T + bo, 256^2 template, fp32 out.
// Grid remap (R7): XCD x owns bm ≡ x (mod 8); bn = k>>2. Bijective.
// ---------------------------------------------------------------------------
__global__ __launch_bounds__(512, 1) void gemm_out(
    const u16* __restrict__ HSm, const u16* __restrict__ Wob,
    const float* __restrict__ bo, float* __restrict__ OUT)
{
    int t = threadIdx.x, w = t >> 6, lane = t & 63, quad = lane >> 4, l16 = lane & 15;
    int wm = w >> 2, wn = w & 3;

    int x = blockIdx.x & 7, k = blockIdx.x >> 3;
    int bm = x + ((k & 3) << 3);          // XCD x owns bm ≡ x (mod 8)
    int bn = k >> 2;
    int m0 = bm << 8, n0 = bn << 8;

    int lr8 = lane >> 3, lg = (lane & 7) ^ lr8;
    const u16* gA = HSm + (size_t)(m0 + w * 8 + lr8) * 2048 + lg * 8;
    const u16* gB = Wob + (size_t)(n0 + w * 8 + lr8) * 2048 + lg * 8;

    f32x4 acc[8][4] = {};
    mm256_loop(gA, gB, w, wm, wn, quad, l16, acc);

#pragma unroll
    for (int i = 0; i < 8; i++) {
#pragma unroll
        for (int j = 0; j < 4; j++) {
            int nc = n0 + wn * 64 + j * 16 + l16;
            float bia = bo[nc];
#pragma unroll
            for (int r = 0; r < 4; r++) {
                int mr = m0 + wm * 128 + i * 16 + quad * 4 + r;
                OUT[(size_t)mr * 2048 + nc] = acc[i][j][r] + bia;
            }
        }
    }
}

// ---------------------------------------------------------------------------
extern "C" void kernel_launch(void* const* d_in, const int* in_sizes, int n_in,
                              void* d_out, int out_size, void* d_ws, size_t ws_size,
                              hipStream_t stream) {
    const float* x    = (const float*)d_in[0];
    const float* cosT = (const float*)d_in[1];
    const float* sinT = (const float*)d_in[2];
    const float* Wq   = (const float*)d_in[3];
    const float* bq   = (const float*)d_in[4];
    const float* Wk   = (const float*)d_in[5];
    const float* bk   = (const float*)d_in[6];
    const float* Wv   = (const float*)d_in[7];
    const float* bv   = (const float*)d_in[8];
    const float* Wo   = (const float*)d_in[9];
    const float* bo   = (const float*)d_in[10];

    char* ws = (char*)d_ws;
    u16*   Wqkvb   = (u16*)(ws);                 // 25,165,824 B
    u16*   Wob     = (u16*)(ws + 25165824);      //  8,388,608 B
    u16*   Xb      = (u16*)(ws + 33554432);      // 33,554,432 B (dead after gemm_qkv)
    float* part    = (float*)(ws + 33554432);    // alias Xb: 16,777,216 B
    u16*   V       = (u16*)(ws + 67108864);      // 33,554,432 B
    u16*   HS      = V;                          // V dead after vk_mfma
    u16*   vkb     = (u16*)(ws + 100663296);     //  1,048,576 B (bf16)
    float* ksumbuf = (float*)(ws + 101711872);   //     16,384 B -> ~101.7 MB total

    // Q, K scratch in d_out (exactly 67,108,864 B); dead before gemm_out writes.
    u16* Q  = (u16*)d_out;
    u16* Kb = (u16*)d_out + 16777216;

    hipMemsetAsync(ksumbuf, 0, 32 * 128 * sizeof(float), stream);
    cast_all<<<16384, 256, 0, stream>>>(x, Wq, Wk, Wv, Wo, Xb, Wqkvb, Wob);
    gemm_qkv<<<768, 512, 0, stream>>>(Xb, Wqkvb, bq, bk, bv, cosT, sinT, Q, Kb, V);
    ksum_kernel<<<dim3(32, 8), 256, 0, stream>>>(Kb, ksumbuf);
    vk_mfma<<<dim3(32, 8), 256, 0, stream>>>(Kb, V, part);
    vk_reduce<<<dim3(32, 8), 256, 0, stream>>>(part, vkb);
    hs_mfma<<<dim3(32, 32), 256, 0, stream>>>(Q, vkb, ksumbuf, HS);
    gemm_out<<<256, 512, 0, stream>>>(HS, Wob, bo, (float*)d_out);
}